// Round 9
// baseline (265.877 us; speedup 1.0000x reference)
//
#include <hip/hip_runtime.h>
#include <math.h>

#define H 1024
#define HEADS 16
#define DH 64
#define FFN_DIM 2048
#define EPS 1e-5f
#define NB 4
#define LL 1024
#define M_ROWS 4096

typedef __attribute__((ext_vector_type(8))) short bf16x8;
typedef __attribute__((ext_vector_type(4))) float f32x4;

__device__ __forceinline__ ushort f2bf(float x) {
    union { float f; unsigned u; } c; c.f = x;
    unsigned u = c.u;
    u += 0x7FFFu + ((u >> 16) & 1u);
    return (ushort)(u >> 16);
}

__device__ __forceinline__ unsigned pack2bf(float a, float b) {
    union { float f; unsigned u; } ca, cb; ca.f = a; cb.f = b;
    const unsigned ua = ca.u + 0x8000u;
    const unsigned ub = cb.u + 0x8000u;
    return (ua >> 16) | (ub & 0xFFFF0000u);
}

#define GLL(gp, lp)                                                         \
    __builtin_amdgcn_global_load_lds(                                       \
        (const __attribute__((address_space(1))) void*)(gp),                \
        (__attribute__((address_space(3))) void*)(lp), 16, 0, 0)

#define WAITV4() asm volatile("s_waitcnt vmcnt(4)" ::: "memory")
#define WAITV2() asm volatile("s_waitcnt vmcnt(2)" ::: "memory")
#define WAITV0() asm volatile("s_waitcnt vmcnt(0)" ::: "memory")
#define BAR() __builtin_amdgcn_s_barrier()

// ------------- bf16 MFMA GEMM: 8 waves, 3-slot pipeline (round-6 best) ---
// A: M x K bf16 row-major.  Bt: N x K bf16 row-major (B transposed).
// C = (A@B + bias) [+relu].  Split-K via gridDim.z (z==0 adds bias,
// fp32 partials to Cf0/Cf1).  qkv: col c -> segment c/1024.
__global__ __launch_bounds__(512, 6)
void gemm_bf16(const ushort* __restrict__ A, const ushort* __restrict__ Bt,
               const float* __restrict__ bias, float* __restrict__ Cf0,
               float* __restrict__ Cf1, ushort* __restrict__ Cb,
               int M, int N, int K, int relu, int qkv)
{
    __shared__ ushort As[3][128 * 32];   // 3 x 8 KB
    __shared__ ushort Bs[3][128 * 32];
    const int tid = threadIdx.x;         // 0..511, 8 waves
    const int l = tid & 63, w = tid >> 6;
    const int wr = w >> 2, wc = w & 3;   // wave tile: 64 rows x 32 cols
    const int g = l >> 4, c0 = l & 15;
    const int brow = blockIdx.y * 128, bcol = blockIdx.x * 128;
    const int z = blockIdx.z;
    const int Ksub = K / gridDim.z;
    const int NS = Ksub >> 5;

    const ushort* Abase = A + (size_t)brow * K + (size_t)z * Ksub;
    const ushort* Bbase = Bt + (size_t)bcol * K + (size_t)z * Ksub;

    f32x4 acc[4][2];
    #pragma unroll
    for (int mi = 0; mi < 4; ++mi)
        #pragma unroll
        for (int ni = 0; ni < 2; ++ni)
            acc[mi][ni] = (f32x4)0.0f;

    auto stage = [&](int buf, int k0) {  // 2 GLL per thread
        const int row = tid >> 2, cp = tid & 3;
        const int c = cp ^ ((row >> 1) & 3);
        const ushort* ga = Abase + (size_t)row * K + k0 + c * 8;
        const ushort* gb = Bbase + (size_t)row * K + k0 + c * 8;
        ushort* la = As[buf] + (size_t)w * 512;   // + lane*16B by HW
        ushort* lb = Bs[buf] + (size_t)w * 512;
        GLL(ga, la);
        GLL(gb, lb);
    };

    stage(0, 0);
    stage(1, 32);
    int scur = 0;
    for (int t = 0; t < NS; ++t) {
        int snext = scur + 2; if (snext >= 3) snext -= 3;
        if (t + 2 < NS) stage(snext, (t + 2) << 5);
        if (t < NS - 2)       WAITV4();
        else if (t == NS - 2) WAITV2();
        else                  WAITV0();
        BAR();

        bf16x8 af[4], bf[2];
        #pragma unroll
        for (int mi = 0; mi < 4; ++mi) {
            const int row = wr * 64 + mi * 16 + c0;
            const int cc = g ^ ((row >> 1) & 3);
            af[mi] = *(const bf16x8*)&As[scur][row * 32 + cc * 8];
        }
        #pragma unroll
        for (int ni = 0; ni < 2; ++ni) {
            const int row = wc * 32 + ni * 16 + c0;
            const int cc = g ^ ((row >> 1) & 3);
            bf[ni] = *(const bf16x8*)&Bs[scur][row * 32 + cc * 8];
        }
        __builtin_amdgcn_s_setprio(1);
        #pragma unroll
        for (int mi = 0; mi < 4; ++mi)
            #pragma unroll
            for (int ni = 0; ni < 2; ++ni)
                acc[mi][ni] = __builtin_amdgcn_mfma_f32_16x16x32_bf16(
                    af[mi], bf[ni], acc[mi][ni], 0, 0, 0);
        __builtin_amdgcn_s_setprio(0);
        BAR();
        scur = scur + 1 == 3 ? 0 : scur + 1;
    }

    float* Cf = (z == 0) ? Cf0 : Cf1;
    const int colg0 = bcol + wc * 32 + c0;
    const int rbase = brow + wr * 64 + (g << 2);
    const int seg   = qkv ? (bcol >> 10) : 0;
    const int Nw    = qkv ? 1024 : N;
    ushort* outb    = qkv ? (Cb + (size_t)seg * 4194304u) : Cb;
    #pragma unroll
    for (int ni = 0; ni < 2; ++ni) {
        const int colg = colg0 + ni * 16;
        const int colw = qkv ? (colg & 1023) : colg;
        const float bv = (z == 0) ? bias[colg] : 0.0f;
        #pragma unroll
        for (int mi = 0; mi < 4; ++mi) {
            #pragma unroll
            for (int j = 0; j < 4; ++j) {
                float v = acc[mi][ni][j] + bv;
                if (relu) v = fmaxf(v, 0.0f);
                const size_t off = (size_t)(rbase + mi * 16 + j) * Nw + colw;
                if (Cf) Cf[off] = v;
                if (Cb) outb[off] = f2bf(v);
            }
        }
    }
}

// ---------------- fused prep: X cast + 6 weight transposes + bias + mask --
__global__ __launch_bounds__(256)
void prep(const float* __restrict__ X, ushort* __restrict__ Xb,
          const float* __restrict__ Wq, const float* __restrict__ Wk,
          const float* __restrict__ Wv, const float* __restrict__ Wo,
          const float* __restrict__ W1, const float* __restrict__ W2,
          ushort* __restrict__ Wqkvt, ushort* __restrict__ Wot,
          ushort* __restrict__ W1t, ushort* __restrict__ W2t,
          const float* __restrict__ bq, const float* __restrict__ bk,
          const float* __restrict__ bv, float* __restrict__ biasqkv,
          const int* __restrict__ mask, int* __restrict__ mfl,
          float* __restrict__ maskout)
{
    const int b = blockIdx.x;
    const int tid = threadIdx.x;

    if (b < 4096) {                       // X fp32 -> bf16
        const int i = b * 256 + tid;
        float4 v = *reinterpret_cast<const float4*>(&X[(size_t)i * 4]);
        ushort4 o;
        o.x = f2bf(v.x); o.y = f2bf(v.y); o.z = f2bf(v.z); o.w = f2bf(v.w);
        *reinterpret_cast<ushort4*>(&Xb[(size_t)i * 4]) = o;
        return;
    }
    int r = b - 4096;
    const float* W = nullptr; ushort* D = nullptr;
    int K = H, N = H; float sc = 1.0f; int blin = 0;
    if (r < 4096) {
        const int which = r >> 10;
        blin = r & 1023;
        switch (which) {
            case 0: W = Wq; D = Wqkvt;               sc = 0.03125f; break;
            case 1: W = Wk; D = Wqkvt + 1024 * 1024; sc = 0.03125f; break;
            case 2: W = Wv; D = Wqkvt + 2048 * 1024; sc = 1.0f;     break;
            default: W = Wo; D = Wot;                sc = 1.0f;     break;
        }
    } else if (r < 4096 + 2048) {
        W = W1; D = W1t; K = H; N = FFN_DIM; blin = r - 4096;
    } else if (r < 4096 + 4096) {
        W = W2; D = W2t; K = FFN_DIM; N = H; blin = r - 4096 - 2048;
    }
    if (W) {
        __shared__ float t[32][33];
        const int nbx = N >> 5;
        const int bx = blin % nbx, by = blin / nbx;
        const int n0 = bx * 32, k0 = by * 32;
        const int tx = tid & 31, ty = tid >> 5;
        #pragma unroll
        for (int rr = 0; rr < 4; ++rr)
            t[ty + rr * 8][tx] = W[(size_t)(k0 + ty + rr * 8) * N + n0 + tx];
        __syncthreads();
        #pragma unroll
        for (int rr = 0; rr < 4; ++rr)
            D[(size_t)(n0 + ty + rr * 8) * K + k0 + tx] =
                f2bf(t[tx][ty + rr * 8] * sc);
        return;
    }
    r -= 8192;
    if (r < 12) {
        const int i = r * 256 + tid;
        if (i < 3072) {
            float v;
            if (i < 1024) v = bq[i] * 0.03125f;
            else if (i < 2048) v = bk[i - 1024] * 0.03125f;
            else v = bv[i - 2048];
            biasqkv[i] = v;
        }
        return;
    }
    if (r == 12) {
        if (tid < NB * 16) {
            const int n = tid >> 4, tile = tid & 15;
            int any = 0;
            for (int j = 0; j < 64; ++j)
                any |= (mask[n * LL + tile * 64 + j] == 0);
            mfl[tid] = any;
        }
        return;
    }
    {
        const int i = (r - 13) * 256 + tid;
        if (i < NB * LL) maskout[i] = (float)mask[i];
    }
}

// ---------------- per-head V transpose: [1024 j][64 d] -> [64 d][1024 j] --
__global__ __launch_bounds__(256)
void transpose_v(const ushort* __restrict__ V, ushort* __restrict__ Vt)
{
    const int nh = blockIdx.y, jt = blockIdx.x;
    const size_t base = (size_t)nh << 16;
    __shared__ ushort t[64][68];
    const int tid = threadIdx.x;
    #pragma unroll
    for (int pass = 0; pass < 4; ++pass) {
        const int j = pass * 16 + (tid >> 4);
        const int d0 = (tid & 15) * 4;
        ushort4 v = *(const ushort4*)&V[base + (size_t)(jt * 64 + j) * 64 + d0];
        t[d0 + 0][j] = v.x; t[d0 + 1][j] = v.y;
        t[d0 + 2][j] = v.z; t[d0 + 3][j] = v.w;
    }
    __syncthreads();
    #pragma unroll
    for (int pass = 0; pass < 4; ++pass) {
        const int d = pass * 16 + (tid >> 4);
        const int j0 = (tid & 15) * 4;
        ushort4 o;
        o.x = t[d][j0 + 0]; o.y = t[d][j0 + 1];
        o.z = t[d][j0 + 2]; o.w = t[d][j0 + 3];
        *(ushort4*)&Vt[base + (size_t)d * 1024 + jt * 64 + j0] = o;
    }
}

// ------ MFMA flash attention: no staging, no barriers, K/V via L1/L2 -----
// K,V tiles are L2-resident (256 KB/head); fragments read directly from
// global with the MFMA lane layout. Only the wave-private P round-trip
// uses LDS -> zero __syncthreads in the kernel.
__global__ __launch_bounds__(256)
void attn_mfma(const ushort* __restrict__ Q, const ushort* __restrict__ K,
               const ushort* __restrict__ Vt, const int* __restrict__ mask,
               const int* __restrict__ mflags, ushort* __restrict__ ctx)
{
    const int nh = blockIdx.y;
    const int n  = nh >> 4;
    const int qb = blockIdx.x;
    const size_t hb = (size_t)nh << 16;
    const ushort* Qh = Q + hb;
    const ushort* Kh = K + hb;
    const ushort* Vh = Vt + hb;
    ushort* Ch = ctx + hb;

    __shared__ ushort Ps[4][16 * 64];   // per-wave P buffer (2 KB each)

    const int tid = threadIdx.x;
    const int l = tid & 63, w = tid >> 6;
    const int g = l >> 4, c0 = l & 15;
    const int fsw = (c0 & 7) << 1;

    unsigned fbits = 0;
    #pragma unroll
    for (int tt = 0; tt < 16; ++tt)
        fbits |= (unsigned)(mflags[n * 16 + tt] != 0) << tt;

    const ushort* qrow = Qh + (size_t)(qb * 64 + w * 16 + c0) * 64;
    const bf16x8 qf0 = *(const bf16x8*)(qrow + g * 8);
    const bf16x8 qf1 = *(const bf16x8*)(qrow + 32 + g * 8);

    f32x4 Oacc[4];
    #pragma unroll
    for (int nd = 0; nd < 4; ++nd) Oacc[nd] = (f32x4)0.0f;
    float lp = 0.0f;

    for (int t = 0; t < 16; ++t) {
        // S^T = K @ Q^T : K A-fragments straight from global (L1/L2)
        f32x4 s[4];
        #pragma unroll
        for (int nb = 0; nb < 4; ++nb) {
            s[nb] = (f32x4)0.0f;
            const ushort* krow = Kh + (size_t)(t * 64 + nb * 16 + c0) * 64;
            bf16x8 kf0 = *(const bf16x8*)(krow + g * 8);
            bf16x8 kf1 = *(const bf16x8*)(krow + 32 + g * 8);
            __builtin_amdgcn_s_setprio(1);
            s[nb] = __builtin_amdgcn_mfma_f32_16x16x32_bf16(kf0, qf0, s[nb], 0, 0, 0);
            s[nb] = __builtin_amdgcn_mfma_f32_16x16x32_bf16(kf1, qf1, s[nb], 0, 0, 0);
            __builtin_amdgcn_s_setprio(0);
        }
        if (fbits >> t & 1) {             // uniform branch; rare path
            #pragma unroll
            for (int nb = 0; nb < 4; ++nb)
                #pragma unroll
                for (int jr = 0; jr < 4; ++jr) {
                    const int key = 16 * nb + 4 * g + jr;
                    if (mask[n * LL + t * 64 + key] == 0)
                        s[nb][jr] = -INFINITY;
                }
        }
        // fixed-max softmax: P = exp(s); per-lane scalar row-sum (q = c0)
        #pragma unroll
        for (int nb = 0; nb < 4; ++nb)
            #pragma unroll
            for (int jr = 0; jr < 4; ++jr) {
                const float pv = __expf(s[nb][jr]);
                s[nb][jr] = pv;
                lp += pv;
            }

        // P -> per-wave LDS (packed b64, granule-XOR swizzled)
        ushort* Pw = Ps[w];
        #pragma unroll
        for (int nb = 0; nb < 4; ++nb) {
            const int gi = (4 * nb + g) ^ fsw;
            uint2 pk;
            pk.x = pack2bf(s[nb][0], s[nb][1]);
            pk.y = pack2bf(s[nb][2], s[nb][3]);
            *(uint2*)&Pw[c0 * 64 + gi * 4] = pk;
        }
        const bf16x8 pa0 = *(const bf16x8*)&Pw[c0 * 64 + ((2 * g) ^ fsw) * 4];
        const bf16x8 pa1 = *(const bf16x8*)&Pw[c0 * 64 + ((8 + 2 * g) ^ fsw) * 4];
        // O += P @ V : V B-fragments straight from global (Vt layout)
        #pragma unroll
        for (int nd = 0; nd < 4; ++nd) {
            const ushort* vrow = Vh + (size_t)(nd * 16 + c0) * 1024 + t * 64;
            bf16x8 vf0 = *(const bf16x8*)(vrow + g * 8);
            bf16x8 vf1 = *(const bf16x8*)(vrow + 32 + g * 8);
            __builtin_amdgcn_s_setprio(1);
            Oacc[nd] = __builtin_amdgcn_mfma_f32_16x16x32_bf16(pa0, vf0, Oacc[nd], 0, 0, 0);
            Oacc[nd] = __builtin_amdgcn_mfma_f32_16x16x32_bf16(pa1, vf1, Oacc[nd], 0, 0, 0);
            __builtin_amdgcn_s_setprio(0);
        }
    }

    float v = lp;
    v += __shfl_xor(v, 16, 64);
    v += __shfl_xor(v, 32, 64);
    float invq[4];
    #pragma unroll
    for (int jr = 0; jr < 4; ++jr) {
        const int src = 20 * g + jr;
        invq[jr] = 1.0f / __shfl(v, src, 64);
    }
    #pragma unroll
    for (int nd = 0; nd < 4; ++nd) {
        #pragma unroll
        for (int jr = 0; jr < 4; ++jr) {
            const int row = qb * 64 + w * 16 + 4 * g + jr;
            Ch[(size_t)row * 64 + nd * 16 + c0] = f2bf(Oacc[nd][jr] * invq[jr]);
        }
    }
}

// ---------------- LayerNorm + residual (optionally 2-input sum) ----------
__global__ __launch_bounds__(256)
void ln_residual(const float* __restrict__ X, const float* __restrict__ X2,
                 const float* __restrict__ g, const float* __restrict__ b,
                 float* __restrict__ outf, ushort* __restrict__ outb)
{
    const int row = blockIdx.x;
    const int tid = threadIdx.x;
    float4 xv = *reinterpret_cast<const float4*>(&X[(size_t)row * H + tid * 4]);
    if (X2) {
        float4 yv = *reinterpret_cast<const float4*>(&X2[(size_t)row * H + tid * 4]);
        xv.x += yv.x; xv.y += yv.y; xv.z += yv.z; xv.w += yv.w;
    }
    float s = xv.x + xv.y + xv.z + xv.w;
    __shared__ float red[8];
    const int lane = tid & 63, wave = tid >> 6;
    #pragma unroll
    for (int off = 32; off > 0; off >>= 1) s += __shfl_down(s, off);
    if (lane == 0) red[wave] = s;
    __syncthreads();
    if (tid == 0)
        red[0] = (red[0] + red[1] + red[2] + red[3]) * (1.0f / H);
    __syncthreads();
    const float mu = red[0];
    const float d0 = xv.x - mu, d1 = xv.y - mu, d2 = xv.z - mu, d3 = xv.w - mu;
    float s2 = d0 * d0 + d1 * d1 + d2 * d2 + d3 * d3;
    #pragma unroll
    for (int off = 32; off > 0; off >>= 1) s2 += __shfl_down(s2, off);
    if (lane == 0) red[4 + wave] = s2;
    __syncthreads();
    if (tid == 0) {
        const float var = (red[4] + red[5] + red[6] + red[7]) * (1.0f / H);
        red[4] = rsqrtf(var + EPS);
    }
    __syncthreads();
    const float rstd = red[4];
    float4 gv = *reinterpret_cast<const float4*>(&g[tid * 4]);
    float4 bv = *reinterpret_cast<const float4*>(&b[tid * 4]);
    float4 ov;
    ov.x = d0 * rstd * gv.x + bv.x + xv.x;
    ov.y = d1 * rstd * gv.y + bv.y + xv.y;
    ov.z = d2 * rstd * gv.z + bv.z + xv.z;
    ov.w = d3 * rstd * gv.w + bv.w + xv.w;
    if (outf)
        *reinterpret_cast<float4*>(&outf[(size_t)row * H + tid * 4]) = ov;
    if (outb) {
        ushort4 ob;
        ob.x = f2bf(ov.x); ob.y = f2bf(ov.y);
        ob.z = f2bf(ov.z); ob.w = f2bf(ov.w);
        *reinterpret_cast<ushort4*>(&outb[(size_t)row * H + tid * 4]) = ob;
    }
}

extern "C" void kernel_launch(void* const* d_in, const int* in_sizes, int n_in,
                              void* d_out, int out_size, void* d_ws, size_t ws_size,
                              hipStream_t stream)
{
    const float* X    = (const float*)d_in[0];
    const int*   mask = (const int*)d_in[1];
    const float* Wq   = (const float*)d_in[2];
    const float* bq   = (const float*)d_in[3];
    const float* Wk   = (const float*)d_in[4];
    const float* bk   = (const float*)d_in[5];
    const float* Wv   = (const float*)d_in[6];
    const float* bv   = (const float*)d_in[7];
    const float* Wo   = (const float*)d_in[8];
    const float* bo   = (const float*)d_in[9];
    const float* g1   = (const float*)d_in[10];
    const float* bln1 = (const float*)d_in[11];
    const float* W1   = (const float*)d_in[12];
    const float* b1   = (const float*)d_in[13];
    const float* W2   = (const float*)d_in[14];
    const float* b2   = (const float*)d_in[15];
    const float* g2   = (const float*)d_in[16];
    const float* bln2 = (const float*)d_in[17];

    char* wsb = (char*)d_ws;
    const size_t MB = 1u << 20;
    // Static layout (all lifetimes checked):
    // [0,24)  : QKV bf16 segs -> P0 fp32 [0,16) -> Fb bf16 [0,16)
    // [16,24) : raw V seg -> ctxb -> x1b -> Q0-head
    // [24,32) : Xb -> P1-head -> Q0-tail
    // [32,40) : Vtb -> P1-tail -> Q1-head
    // [40,44) : W1t -> Q1-part     [44,46): Wot -> Q1-part
    // [46,48) : biasqkv+mfl -> Q1-part
    // [48,52) : W2t               [52,58): Wqkvt
    ushort* Qb16  = (ushort*)(wsb);
    ushort* ctxb  = (ushort*)(wsb + 16 * MB);
    ushort* x1b   = (ushort*)(wsb + 16 * MB);
    ushort* Xb    = (ushort*)(wsb + 24 * MB);
    ushort* Vtb   = (ushort*)(wsb + 32 * MB);
    ushort* W1t   = (ushort*)(wsb + 40 * MB);
    ushort* Wot   = (ushort*)(wsb + 44 * MB);
    float*  biasqkv = (float*)(wsb + 46 * MB);
    int*    mfl     = (int*)(wsb + 46 * MB + 16384);
    ushort* W2t   = (ushort*)(wsb + 48 * MB);
    ushort* Wqkvt = (ushort*)(wsb + 52 * MB);
    float*  P0 = (float*)(wsb);
    float*  P1 = (float*)(wsb + 24 * MB);
    ushort* Fb = (ushort*)(wsb);
    float*  Q0 = (float*)(wsb + 16 * MB);
    float*  Q1 = (float*)(wsb + 32 * MB);

    dim3 blk(256), gblk(512);

    prep<<<dim3(4096 + 4096 + 2048 + 2048 + 12 + 1 + 16), blk, 0, stream>>>(
        X, Xb, Wq, Wk, Wv, Wo, W1, W2, Wqkvt, Wot, W1t, W2t,
        bq, bk, bv, biasqkv, mask, mfl,
        (float*)d_out + (size_t)M_ROWS * H);

    gemm_bf16<<<dim3(24, 32, 1), gblk, 0, stream>>>(
        Xb, Wqkvt, biasqkv, nullptr, nullptr, Qb16, M_ROWS, 3072, H, 0, 1);
    transpose_v<<<dim3(16, NB * HEADS), blk, 0, stream>>>(
        Qb16 + 2u * 4194304u, Vtb);

    attn_mfma<<<dim3(16, NB * HEADS), blk, 0, stream>>>(
        Qb16, Qb16 + 4194304u, Vtb, mask, mfl, ctxb);

    gemm_bf16<<<dim3(8, 32, 2), gblk, 0, stream>>>(
        ctxb, Wot, bo, P0, P1, nullptr, M_ROWS, H, H, 0, 0);
    ln_residual<<<dim3(M_ROWS), blk, 0, stream>>>(P0, P1, g1, bln1,
                                                  nullptr, x1b);

    gemm_bf16<<<dim3(16, 32, 1), gblk, 0, stream>>>(
        x1b, W1t, b1, nullptr, nullptr, Fb, M_ROWS, FFN_DIM, H, 1, 0);
    gemm_bf16<<<dim3(8, 32, 2), gblk, 0, stream>>>(
        Fb, W2t, b2, Q0, Q1, nullptr, M_ROWS, H, FFN_DIM, 0, 0);

    ln_residual<<<dim3(M_ROWS), blk, 0, stream>>>(Q0, Q1, g2, bln2,
                                                  (float*)d_out, nullptr);
}

// Round 12
// 184.623 us; speedup vs baseline: 1.4401x; 1.4401x over previous
//
#include <hip/hip_runtime.h>
#include <math.h>

#define H 1024
#define HEADS 16
#define DH 64
#define FFN_DIM 2048
#define EPS 1e-5f
#define NB 4
#define LL 1024
#define M_ROWS 4096

typedef __attribute__((ext_vector_type(8))) short bf16x8;
typedef __attribute__((ext_vector_type(4))) float f32x4;

__device__ __forceinline__ ushort f2bf(float x) {
    union { float f; unsigned u; } c; c.f = x;
    unsigned u = c.u;
    u += 0x7FFFu + ((u >> 16) & 1u);
    return (ushort)(u >> 16);
}

__device__ __forceinline__ unsigned pack2bf(float a, float b) {
    union { float f; unsigned u; } ca, cb; ca.f = a; cb.f = b;
    const unsigned ua = ca.u + 0x8000u;
    const unsigned ub = cb.u + 0x8000u;
    return (ua >> 16) | (ub & 0xFFFF0000u);
}

#define GLL(gp, lp)                                                         \
    __builtin_amdgcn_global_load_lds(                                       \
        (const __attribute__((address_space(1))) void*)(gp),                \
        (__attribute__((address_space(3))) void*)(lp), 16, 0, 0)

#define WAITV4() asm volatile("s_waitcnt vmcnt(4)" ::: "memory")
#define WAITV2() asm volatile("s_waitcnt vmcnt(2)" ::: "memory")
#define WAITV0() asm volatile("s_waitcnt vmcnt(0)" ::: "memory")
#define BAR() __builtin_amdgcn_s_barrier()

// ------------- bf16 MFMA GEMM: 8 waves, 3-slot pipeline (round-6 best) ---
// A: M x K bf16 row-major.  Bt: N x K bf16 row-major (B transposed).
// C = (A@B + bias) [+relu].  Split-K via gridDim.z (z==0 adds bias,
// fp32 partials to Cf0/Cf1).  qkv: output col c -> segment c/1024, linear
// token-major write.  NOTE: do NOT fuse the per-head V transpose here —
// the (N,L,H)->(N,16,L,64) reshape is a REINTERPRET: head = token>>6
// (token-derived), head-row j = (token&63)*16 + (feat>>6), dd = feat&63.
// Round-10 tried feature-derived heads and produced garbage (absmax 8.5);
// the correct mapping is uncoalescible from this epilogue.
__global__ __launch_bounds__(512, 6)
void gemm_bf16(const ushort* __restrict__ A, const ushort* __restrict__ Bt,
               const float* __restrict__ bias, float* __restrict__ Cf0,
               float* __restrict__ Cf1, ushort* __restrict__ Cb,
               int M, int N, int K, int relu, int qkv)
{
    __shared__ ushort As[3][128 * 32];   // 3 x 8 KB
    __shared__ ushort Bs[3][128 * 32];
    const int tid = threadIdx.x;         // 0..511, 8 waves
    const int l = tid & 63, w = tid >> 6;
    const int wr = w >> 2, wc = w & 3;   // wave tile: 64 rows x 32 cols
    const int g = l >> 4, c0 = l & 15;
    const int brow = blockIdx.y * 128, bcol = blockIdx.x * 128;
    const int z = blockIdx.z;
    const int Ksub = K / gridDim.z;
    const int NS = Ksub >> 5;

    const ushort* Abase = A + (size_t)brow * K + (size_t)z * Ksub;
    const ushort* Bbase = Bt + (size_t)bcol * K + (size_t)z * Ksub;

    f32x4 acc[4][2];
    #pragma unroll
    for (int mi = 0; mi < 4; ++mi)
        #pragma unroll
        for (int ni = 0; ni < 2; ++ni)
            acc[mi][ni] = (f32x4)0.0f;

    auto stage = [&](int buf, int k0) {  // 2 GLL per thread
        const int row = tid >> 2, cp = tid & 3;
        const int c = cp ^ ((row >> 1) & 3);
        const ushort* ga = Abase + (size_t)row * K + k0 + c * 8;
        const ushort* gb = Bbase + (size_t)row * K + k0 + c * 8;
        ushort* la = As[buf] + (size_t)w * 512;   // + lane*16B by HW
        ushort* lb = Bs[buf] + (size_t)w * 512;
        GLL(ga, la);
        GLL(gb, lb);
    };

    stage(0, 0);
    stage(1, 32);
    int scur = 0;
    for (int t = 0; t < NS; ++t) {
        int snext = scur + 2; if (snext >= 3) snext -= 3;
        if (t + 2 < NS) stage(snext, (t + 2) << 5);
        if (t < NS - 2)       WAITV4();
        else if (t == NS - 2) WAITV2();
        else                  WAITV0();
        BAR();

        bf16x8 af[4], bf[2];
        #pragma unroll
        for (int mi = 0; mi < 4; ++mi) {
            const int row = wr * 64 + mi * 16 + c0;
            const int cc = g ^ ((row >> 1) & 3);
            af[mi] = *(const bf16x8*)&As[scur][row * 32 + cc * 8];
        }
        #pragma unroll
        for (int ni = 0; ni < 2; ++ni) {
            const int row = wc * 32 + ni * 16 + c0;
            const int cc = g ^ ((row >> 1) & 3);
            bf[ni] = *(const bf16x8*)&Bs[scur][row * 32 + cc * 8];
        }
        __builtin_amdgcn_s_setprio(1);
        #pragma unroll
        for (int mi = 0; mi < 4; ++mi)
            #pragma unroll
            for (int ni = 0; ni < 2; ++ni)
                acc[mi][ni] = __builtin_amdgcn_mfma_f32_16x16x32_bf16(
                    af[mi], bf[ni], acc[mi][ni], 0, 0, 0);
        __builtin_amdgcn_s_setprio(0);
        BAR();
        scur = scur + 1 == 3 ? 0 : scur + 1;
    }

    float* Cf = (z == 0) ? Cf0 : Cf1;
    const int colg0 = bcol + wc * 32 + c0;
    const int rbase = brow + wr * 64 + (g << 2);
    const int seg   = qkv ? (bcol >> 10) : 0;
    const int Nw    = qkv ? 1024 : N;
    ushort* outb    = qkv ? (Cb + (size_t)seg * 4194304u) : Cb;
    #pragma unroll
    for (int ni = 0; ni < 2; ++ni) {
        const int colg = colg0 + ni * 16;
        const int colw = qkv ? (colg & 1023) : colg;
        const float bv = (z == 0) ? bias[colg] : 0.0f;
        #pragma unroll
        for (int mi = 0; mi < 4; ++mi) {
            #pragma unroll
            for (int j = 0; j < 4; ++j) {
                float v = acc[mi][ni][j] + bv;
                if (relu) v = fmaxf(v, 0.0f);
                const size_t off = (size_t)(rbase + mi * 16 + j) * Nw + colw;
                if (Cf) Cf[off] = v;
                if (Cb) outb[off] = f2bf(v);
            }
        }
    }
}

// ---------------- fused prep: X cast + 6 weight transposes + bias + mask --
__global__ __launch_bounds__(256)
void prep(const float* __restrict__ X, ushort* __restrict__ Xb,
          const float* __restrict__ Wq, const float* __restrict__ Wk,
          const float* __restrict__ Wv, const float* __restrict__ Wo,
          const float* __restrict__ W1, const float* __restrict__ W2,
          ushort* __restrict__ Wqkvt, ushort* __restrict__ Wot,
          ushort* __restrict__ W1t, ushort* __restrict__ W2t,
          const float* __restrict__ bq, const float* __restrict__ bk,
          const float* __restrict__ bv, float* __restrict__ biasqkv,
          const int* __restrict__ mask, int* __restrict__ mfl,
          float* __restrict__ maskout)
{
    const int b = blockIdx.x;
    const int tid = threadIdx.x;

    if (b < 4096) {                       // X fp32 -> bf16
        const int i = b * 256 + tid;
        float4 v = *reinterpret_cast<const float4*>(&X[(size_t)i * 4]);
        ushort4 o;
        o.x = f2bf(v.x); o.y = f2bf(v.y); o.z = f2bf(v.z); o.w = f2bf(v.w);
        *reinterpret_cast<ushort4*>(&Xb[(size_t)i * 4]) = o;
        return;
    }
    int r = b - 4096;
    const float* W = nullptr; ushort* D = nullptr;
    int K = H, N = H; float sc = 1.0f; int blin = 0;
    if (r < 4096) {
        const int which = r >> 10;
        blin = r & 1023;
        switch (which) {
            case 0: W = Wq; D = Wqkvt;               sc = 0.03125f; break;
            case 1: W = Wk; D = Wqkvt + 1024 * 1024; sc = 0.03125f; break;
            case 2: W = Wv; D = Wqkvt + 2048 * 1024; sc = 1.0f;     break;
            default: W = Wo; D = Wot;                sc = 1.0f;     break;
        }
    } else if (r < 4096 + 2048) {
        W = W1; D = W1t; K = H; N = FFN_DIM; blin = r - 4096;
    } else if (r < 4096 + 4096) {
        W = W2; D = W2t; K = FFN_DIM; N = H; blin = r - 4096 - 2048;
    }
    if (W) {
        __shared__ float t[32][33];
        const int nbx = N >> 5;
        const int bx = blin % nbx, by = blin / nbx;
        const int n0 = bx * 32, k0 = by * 32;
        const int tx = tid & 31, ty = tid >> 5;
        #pragma unroll
        for (int rr = 0; rr < 4; ++rr)
            t[ty + rr * 8][tx] = W[(size_t)(k0 + ty + rr * 8) * N + n0 + tx];
        __syncthreads();
        #pragma unroll
        for (int rr = 0; rr < 4; ++rr)
            D[(size_t)(n0 + ty + rr * 8) * K + k0 + tx] =
                f2bf(t[tx][ty + rr * 8] * sc);
        return;
    }
    r -= 8192;
    if (r < 12) {
        const int i = r * 256 + tid;
        if (i < 3072) {
            float v;
            if (i < 1024) v = bq[i] * 0.03125f;
            else if (i < 2048) v = bk[i - 1024] * 0.03125f;
            else v = bv[i - 2048];
            biasqkv[i] = v;
        }
        return;
    }
    if (r == 12) {
        if (tid < NB * 16) {
            const int n = tid >> 4, tile = tid & 15;
            int any = 0;
            for (int j = 0; j < 64; ++j)
                any |= (mask[n * LL + tile * 64 + j] == 0);
            mfl[tid] = any;
        }
        return;
    }
    {
        const int i = (r - 13) * 256 + tid;
        if (i < NB * LL) maskout[i] = (float)mask[i];
    }
}

// ---------------- per-head V transpose: [1024 j][64 d] -> [64 d][1024 j] --
// head block = contiguous 65536-elem chunk at nh<<16 (reinterpret semantics)
__global__ __launch_bounds__(256)
void transpose_v(const ushort* __restrict__ V, ushort* __restrict__ Vt)
{
    const int nh = blockIdx.y, jt = blockIdx.x;
    const size_t base = (size_t)nh << 16;
    __shared__ ushort t[64][68];
    const int tid = threadIdx.x;
    #pragma unroll
    for (int pass = 0; pass < 4; ++pass) {
        const int j = pass * 16 + (tid >> 4);
        const int d0 = (tid & 15) * 4;
        ushort4 v = *(const ushort4*)&V[base + (size_t)(jt * 64 + j) * 64 + d0];
        t[d0 + 0][j] = v.x; t[d0 + 1][j] = v.y;
        t[d0 + 2][j] = v.z; t[d0 + 3][j] = v.w;
    }
    __syncthreads();
    #pragma unroll
    for (int pass = 0; pass < 4; ++pass) {
        const int d = pass * 16 + (tid >> 4);
        const int j0 = (tid & 15) * 4;
        ushort4 o;
        o.x = t[d][j0 + 0]; o.y = t[d][j0 + 1];
        o.z = t[d][j0 + 2]; o.w = t[d][j0 + 3];
        *(ushort4*)&Vt[base + (size_t)d * 1024 + jt * 64 + j0] = o;
    }
}

// ------------- MFMA flash attention: swapped QK^T, packed P, staged ------
// PROVEN round-7 structure. Do NOT replace LDS staging with direct global
// fragment reads: round-9 tried it and regressed 45->123 us (16 scattered
// cache-line transactions per MFMA operand + 1e6 LDS bank conflicts).
__global__ __launch_bounds__(256)
void attn_mfma(const ushort* __restrict__ Q, const ushort* __restrict__ K,
               const ushort* __restrict__ Vt, const int* __restrict__ mask,
               const int* __restrict__ mflags, ushort* __restrict__ ctx)
{
    const int nh = blockIdx.y;
    const int n  = nh >> 4;
    const int qb = blockIdx.x;
    const size_t hb = (size_t)nh << 16;
    const ushort* Qh = Q + hb;
    const ushort* Kh = K + hb;
    const ushort* Vh = Vt + hb;
    ushort* Ch = ctx + hb;

    __shared__ ushort Ks[2][64 * 64];
    __shared__ ushort Vs[2][64 * 64];
    __shared__ ushort Ps[4][16 * 64];

    const int tid = threadIdx.x;
    const int l = tid & 63, w = tid >> 6;
    const int g = l >> 4, c0 = l & 15;
    const int fsw = (c0 & 7) << 1;

    unsigned fbits = 0;
    #pragma unroll
    for (int tt = 0; tt < 16; ++tt)
        fbits |= (unsigned)(mflags[n * 16 + tt] != 0) << tt;

    const ushort* qrow = Qh + (size_t)(qb * 64 + w * 16 + c0) * 64;
    const bf16x8 qf0 = *(const bf16x8*)(qrow + g * 8);
    const bf16x8 qf1 = *(const bf16x8*)(qrow + 32 + g * 8);

    f32x4 Oacc[4];
    #pragma unroll
    for (int nd = 0; nd < 4; ++nd) Oacc[nd] = (f32x4)0.0f;
    float lp = 0.0f;

    auto stage = [&](int buf, int t) {
        #pragma unroll
        for (int i = 0; i < 2; ++i) {
            const int slot = i * 256 + tid;
            const int r = slot >> 3, p = slot & 7;
            const int c = p ^ (r & 7);
            const ushort* gk = Kh + (size_t)(t * 64 + r) * 64 + c * 8;
            const ushort* gv = Vh + (size_t)r * 1024 + t * 64 + c * 8;
            ushort* lk = Ks[buf] + (size_t)(i * 256 + w * 64) * 8;
            ushort* lv = Vs[buf] + (size_t)(i * 256 + w * 64) * 8;
            GLL(gk, lk);
            GLL(gv, lv);
        }
    };

    stage(0, 0);
    int cur = 0;
    for (int t = 0; t < 16; ++t) {
        if (t < 15) { stage(cur ^ 1, t + 1); WAITV4(); }
        else        { WAITV0(); }
        BAR();

        // S^T = K @ Q^T : col = q = c0; rows = keys 16nb + 4g + jr
        f32x4 s[4];
        #pragma unroll
        for (int nb = 0; nb < 4; ++nb) {
            s[nb] = (f32x4)0.0f;
            const int row = nb * 16 + c0;
            const int cc0 = g ^ (row & 7);
            const int cc1 = (4 + g) ^ (row & 7);
            bf16x8 kf0 = *(const bf16x8*)&Ks[cur][row * 64 + cc0 * 8];
            bf16x8 kf1 = *(const bf16x8*)&Ks[cur][row * 64 + cc1 * 8];
            __builtin_amdgcn_s_setprio(1);
            s[nb] = __builtin_amdgcn_mfma_f32_16x16x32_bf16(kf0, qf0, s[nb], 0, 0, 0);
            s[nb] = __builtin_amdgcn_mfma_f32_16x16x32_bf16(kf1, qf1, s[nb], 0, 0, 0);
            __builtin_amdgcn_s_setprio(0);
        }
        if (fbits >> t & 1) {             // uniform branch; rare path
            #pragma unroll
            for (int nb = 0; nb < 4; ++nb)
                #pragma unroll
                for (int jr = 0; jr < 4; ++jr) {
                    const int key = 16 * nb + 4 * g + jr;
                    if (mask[n * LL + t * 64 + key] == 0)
                        s[nb][jr] = -INFINITY;
                }
        }
        // fixed-max softmax: P = exp(s); per-lane scalar row-sum (q = c0)
        #pragma unroll
        for (int nb = 0; nb < 4; ++nb)
            #pragma unroll
            for (int jr = 0; jr < 4; ++jr) {
                const float pv = __expf(s[nb][jr]);
                s[nb][jr] = pv;
                lp += pv;
            }

        // P -> per-wave LDS (packed b64, granule-XOR swizzled)
        ushort* Pw = Ps[w];
        #pragma unroll
        for (int nb = 0; nb < 4; ++nb) {
            const int gi = (4 * nb + g) ^ fsw;
            uint2 pk;
            pk.x = pack2bf(s[nb][0], s[nb][1]);
            pk.y = pack2bf(s[nb][2], s[nb][3]);
            *(uint2*)&Pw[c0 * 64 + gi * 4] = pk;
        }
        const bf16x8 pa0 = *(const bf16x8*)&Pw[c0 * 64 + ((2 * g) ^ fsw) * 4];
        const bf16x8 pa1 = *(const bf16x8*)&Pw[c0 * 64 + ((8 + 2 * g) ^ fsw) * 4];
        // O += P @ V
        #pragma unroll
        for (int nd = 0; nd < 4; ++nd) {
            const int row = nd * 16 + c0;
            const int cc0 = g ^ (row & 7);
            const int cc1 = (4 + g) ^ (row & 7);
            bf16x8 vf0 = *(const bf16x8*)&Vs[cur][row * 64 + cc0 * 8];
            bf16x8 vf1 = *(const bf16x8*)&Vs[cur][row * 64 + cc1 * 8];
            __builtin_amdgcn_s_setprio(1);
            Oacc[nd] = __builtin_amdgcn_mfma_f32_16x16x32_bf16(pa0, vf0, Oacc[nd], 0, 0, 0);
            Oacc[nd] = __builtin_amdgcn_mfma_f32_16x16x32_bf16(pa1, vf1, Oacc[nd], 0, 0, 0);
            __builtin_amdgcn_s_setprio(0);
        }
        BAR();
        cur ^= 1;
    }

    float v = lp;
    v += __shfl_xor(v, 16, 64);
    v += __shfl_xor(v, 32, 64);
    float invq[4];
    #pragma unroll
    for (int jr = 0; jr < 4; ++jr) {
        const int src = 20 * g + jr;
        invq[jr] = 1.0f / __shfl(v, src, 64);
    }
    #pragma unroll
    for (int nd = 0; nd < 4; ++nd) {
        #pragma unroll
        for (int jr = 0; jr < 4; ++jr) {
            const int row = qb * 64 + w * 16 + 4 * g + jr;
            Ch[(size_t)row * 64 + nd * 16 + c0] = f2bf(Oacc[nd][jr] * invq[jr]);
        }
    }
}

// ---------------- LayerNorm + residual (optionally 2-input sum) ----------
__global__ __launch_bounds__(256)
void ln_residual(const float* __restrict__ X, const float* __restrict__ X2,
                 const float* __restrict__ g, const float* __restrict__ b,
                 float* __restrict__ outf, ushort* __restrict__ outb)
{
    const int row = blockIdx.x;
    const int tid = threadIdx.x;
    float4 xv = *reinterpret_cast<const float4*>(&X[(size_t)row * H + tid * 4]);
    if (X2) {
        float4 yv = *reinterpret_cast<const float4*>(&X2[(size_t)row * H + tid * 4]);
        xv.x += yv.x; xv.y += yv.y; xv.z += yv.z; xv.w += yv.w;
    }
    float s = xv.x + xv.y + xv.z + xv.w;
    __shared__ float red[8];
    const int lane = tid & 63, wave = tid >> 6;
    #pragma unroll
    for (int off = 32; off > 0; off >>= 1) s += __shfl_down(s, off);
    if (lane == 0) red[wave] = s;
    __syncthreads();
    if (tid == 0)
        red[0] = (red[0] + red[1] + red[2] + red[3]) * (1.0f / H);
    __syncthreads();
    const float mu = red[0];
    const float d0 = xv.x - mu, d1 = xv.y - mu, d2 = xv.z - mu, d3 = xv.w - mu;
    float s2 = d0 * d0 + d1 * d1 + d2 * d2 + d3 * d3;
    #pragma unroll
    for (int off = 32; off > 0; off >>= 1) s2 += __shfl_down(s2, off);
    if (lane == 0) red[4 + wave] = s2;
    __syncthreads();
    if (tid == 0) {
        const float var = (red[4] + red[5] + red[6] + red[7]) * (1.0f / H);
        red[4] = rsqrtf(var + EPS);
    }
    __syncthreads();
    const float rstd = red[4];
    float4 gv = *reinterpret_cast<const float4*>(&g[tid * 4]);
    float4 bv = *reinterpret_cast<const float4*>(&b[tid * 4]);
    float4 ov;
    ov.x = d0 * rstd * gv.x + bv.x + xv.x;
    ov.y = d1 * rstd * gv.y + bv.y + xv.y;
    ov.z = d2 * rstd * gv.z + bv.z + xv.z;
    ov.w = d3 * rstd * gv.w + bv.w + xv.w;
    if (outf)
        *reinterpret_cast<float4*>(&outf[(size_t)row * H + tid * 4]) = ov;
    if (outb) {
        ushort4 ob;
        ob.x = f2bf(ov.x); ob.y = f2bf(ov.y);
        ob.z = f2bf(ov.z); ob.w = f2bf(ov.w);
        *reinterpret_cast<ushort4*>(&outb[(size_t)row * H + tid * 4]) = ob;
    }
}

extern "C" void kernel_launch(void* const* d_in, const int* in_sizes, int n_in,
                              void* d_out, int out_size, void* d_ws, size_t ws_size,
                              hipStream_t stream)
{
    const float* X    = (const float*)d_in[0];
    const int*   mask = (const int*)d_in[1];
    const float* Wq   = (const float*)d_in[2];
    const float* bq   = (const float*)d_in[3];
    const float* Wk   = (const float*)d_in[4];
    const float* bk   = (const float*)d_in[5];
    const float* Wv   = (const float*)d_in[6];
    const float* bv   = (const float*)d_in[7];
    const float* Wo   = (const float*)d_in[8];
    const float* bo   = (const float*)d_in[9];
    const float* g1   = (const float*)d_in[10];
    const float* bln1 = (const float*)d_in[11];
    const float* W1   = (const float*)d_in[12];
    const float* b1   = (const float*)d_in[13];
    const float* W2   = (const float*)d_in[14];
    const float* b2   = (const float*)d_in[15];
    const float* g2   = (const float*)d_in[16];
    const float* bln2 = (const float*)d_in[17];

    char* wsb = (char*)d_ws;
    const size_t MB = 1u << 20;
    // Layout (lifetimes checked; round-9-proven):
    // [0,24)  : QKV bf16 segs (Q@0, K@8, V@16) -> P0 fp32 [0,16) -> Fb bf16
    // [16,24) : V seg -> ctxb (after transpose_v) -> x1b -> Q0-head
    // [24,32) : Xb -> P1 -> Q0-tail
    // [32,40) : Vtb -> Q1-head
    // [40,44) : W1t          [44,46): Wot    [46,48): biasqkv+mfl  (Q1 covers)
    // [48,52) : W2t          [52,58): Wqkvt
    ushort* Qb16  = (ushort*)(wsb);
    ushort* Vb16  = (ushort*)(wsb + 16 * MB);
    ushort* ctxb  = (ushort*)(wsb + 16 * MB);
    ushort* x1b   = (ushort*)(wsb + 16 * MB);
    ushort* Xb    = (ushort*)(wsb + 24 * MB);
    ushort* Vtb   = (ushort*)(wsb + 32 * MB);
    ushort* W1t   = (ushort*)(wsb + 40 * MB);
    ushort* Wot   = (ushort*)(wsb + 44 * MB);
    float*  biasqkv = (float*)(wsb + 46 * MB);
    int*    mfl     = (int*)(wsb + 46 * MB + 16384);
    ushort* W2t   = (ushort*)(wsb + 48 * MB);
    ushort* Wqkvt = (ushort*)(wsb + 52 * MB);
    float*  P0 = (float*)(wsb);
    float*  P1 = (float*)(wsb + 24 * MB);
    ushort* Fb = (ushort*)(wsb);
    float*  Q0 = (float*)(wsb + 16 * MB);
    float*  Q1 = (float*)(wsb + 32 * MB);

    dim3 blk(256), gblk(512);

    prep<<<dim3(4096 + 4096 + 2048 + 2048 + 12 + 1 + 16), blk, 0, stream>>>(
        X, Xb, Wq, Wk, Wv, Wo, W1, W2, Wqkvt, Wot, W1t, W2t,
        bq, bk, bv, biasqkv, mask, mfl,
        (float*)d_out + (size_t)M_ROWS * H);

    // fused QKV: N=3072, linear bf16 segments
    gemm_bf16<<<dim3(24, 32, 1), gblk, 0, stream>>>(
        Xb, Wqkvt, biasqkv, nullptr, nullptr, Qb16, M_ROWS, 3072, H, 0, 1);
    transpose_v<<<dim3(16, NB * HEADS), blk, 0, stream>>>(Vb16, Vtb);

    attn_mfma<<<dim3(16, NB * HEADS), blk, 0, stream>>>(
        Qb16, Qb16 + 4194304u, Vtb, mask, mfl, ctxb);

    gemm_bf16<<<dim3(8, 32, 2), gblk, 0, stream>>>(
        ctxb, Wot, bo, P0, P1, nullptr, M_ROWS, H, H, 0, 0);
    ln_residual<<<dim3(M_ROWS), blk, 0, stream>>>(P0, P1, g1, bln1,
                                                  nullptr, x1b);

    gemm_bf16<<<dim3(16, 32, 1), gblk, 0, stream>>>(
        x1b, W1t, b1, nullptr, nullptr, Fb, M_ROWS, FFN_DIM, H, 1, 0);
    gemm_bf16<<<dim3(8, 32, 2), gblk, 0, stream>>>(
        Fb, W2t, b2, Q0, Q1, nullptr, M_ROWS, H, FFN_DIM, 0, 0);

    ln_residual<<<dim3(M_ROWS), blk, 0, stream>>>(Q0, Q1, g2, bln2,
                                                  (float*)d_out, nullptr);
}

// Round 13
// 177.790 us; speedup vs baseline: 1.4955x; 1.0384x over previous
//
#include <hip/hip_runtime.h>
#include <math.h>

#define H 1024
#define HEADS 16
#define DH 64
#define FFN_DIM 2048
#define EPS 1e-5f
#define NB 4
#define LL 1024
#define M_ROWS 4096

typedef __attribute__((ext_vector_type(8))) short bf16x8;
typedef __attribute__((ext_vector_type(4))) float f32x4;

__device__ __forceinline__ ushort f2bf(float x) {
    union { float f; unsigned u; } c; c.f = x;
    unsigned u = c.u;
    u += 0x7FFFu + ((u >> 16) & 1u);
    return (ushort)(u >> 16);
}

__device__ __forceinline__ unsigned pack2bf(float a, float b) {
    union { float f; unsigned u; } ca, cb; ca.f = a; cb.f = b;
    const unsigned ua = ca.u + 0x8000u;
    const unsigned ub = cb.u + 0x8000u;
    return (ua >> 16) | (ub & 0xFFFF0000u);
}

#define GLL(gp, lp)                                                         \
    __builtin_amdgcn_global_load_lds(                                       \
        (const __attribute__((address_space(1))) void*)(gp),                \
        (__attribute__((address_space(3))) void*)(lp), 16, 0, 0)

#define WAITV4() asm volatile("s_waitcnt vmcnt(4)" ::: "memory")
#define WAITV2() asm volatile("s_waitcnt vmcnt(2)" ::: "memory")
#define WAITV0() asm volatile("s_waitcnt vmcnt(0)" ::: "memory")
#define BAR() __builtin_amdgcn_s_barrier()

// bijective XCD swizzle (m204): contiguous grid chunk per XCD for L2 reuse
__device__ __forceinline__ void xcd_swizzle(int nx, int ny, int& bx, int& by)
{
    const int nwg = nx * ny;
    int bid = by * nx + bx;
    const int q = nwg >> 3, r = nwg & 7;
    const int xcd = bid & 7, i = bid >> 3;
    bid = (xcd < r) ? (xcd * (q + 1) + i)
                    : (r * (q + 1) + (xcd - r) * q + i);
    bx = bid % nx; by = bid / nx;
}

// ------------- bf16 MFMA GEMM: 8 waves, 3-slot pipeline (round-6 best) ---
// A: M x K bf16 row-major.  Bt: N x K bf16 row-major (B transposed).
// C = (A@B + bias) [+relu].  Split-K via gridDim.z (z==0 adds bias,
// fp32 partials to Cf0/Cf1).  qkv: output col c -> segment c/1024, linear
// token-major write.  NOTE: do NOT fuse the per-head V transpose here —
// the (N,L,H)->(N,16,L,64) reshape is a REINTERPRET: head = token>>6
// (token-derived).  Round-10 tried feature-derived heads -> absmax 8.5.
__global__ __launch_bounds__(512, 6)
void gemm_bf16(const ushort* __restrict__ A, const ushort* __restrict__ Bt,
               const float* __restrict__ bias, float* __restrict__ Cf0,
               float* __restrict__ Cf1, ushort* __restrict__ Cb,
               int M, int N, int K, int relu, int qkv)
{
    __shared__ ushort As[3][128 * 32];   // 3 x 8 KB
    __shared__ ushort Bs[3][128 * 32];
    const int tid = threadIdx.x;         // 0..511, 8 waves
    const int l = tid & 63, w = tid >> 6;
    const int wr = w >> 2, wc = w & 3;   // wave tile: 64 rows x 32 cols
    const int g = l >> 4, c0 = l & 15;
    int bxs = blockIdx.x, bys = blockIdx.y;
    xcd_swizzle(gridDim.x, gridDim.y, bxs, bys);
    const int brow = bys * 128, bcol = bxs * 128;
    const int z = blockIdx.z;
    const int Ksub = K / gridDim.z;
    const int NS = Ksub >> 5;

    const ushort* Abase = A + (size_t)brow * K + (size_t)z * Ksub;
    const ushort* Bbase = Bt + (size_t)bcol * K + (size_t)z * Ksub;

    f32x4 acc[4][2];
    #pragma unroll
    for (int mi = 0; mi < 4; ++mi)
        #pragma unroll
        for (int ni = 0; ni < 2; ++ni)
            acc[mi][ni] = (f32x4)0.0f;

    auto stage = [&](int buf, int k0) {  // 2 GLL per thread
        const int row = tid >> 2, cp = tid & 3;
        const int c = cp ^ ((row >> 1) & 3);
        const ushort* ga = Abase + (size_t)row * K + k0 + c * 8;
        const ushort* gb = Bbase + (size_t)row * K + k0 + c * 8;
        ushort* la = As[buf] + (size_t)w * 512;   // + lane*16B by HW
        ushort* lb = Bs[buf] + (size_t)w * 512;
        GLL(ga, la);
        GLL(gb, lb);
    };

    stage(0, 0);
    stage(1, 32);
    int scur = 0;
    for (int t = 0; t < NS; ++t) {
        int snext = scur + 2; if (snext >= 3) snext -= 3;
        if (t + 2 < NS) stage(snext, (t + 2) << 5);
        if (t < NS - 2)       WAITV4();
        else if (t == NS - 2) WAITV2();
        else                  WAITV0();
        BAR();

        bf16x8 af[4], bf[2];
        #pragma unroll
        for (int mi = 0; mi < 4; ++mi) {
            const int row = wr * 64 + mi * 16 + c0;
            const int cc = g ^ ((row >> 1) & 3);
            af[mi] = *(const bf16x8*)&As[scur][row * 32 + cc * 8];
        }
        #pragma unroll
        for (int ni = 0; ni < 2; ++ni) {
            const int row = wc * 32 + ni * 16 + c0;
            const int cc = g ^ ((row >> 1) & 3);
            bf[ni] = *(const bf16x8*)&Bs[scur][row * 32 + cc * 8];
        }
        __builtin_amdgcn_s_setprio(1);
        #pragma unroll
        for (int mi = 0; mi < 4; ++mi)
            #pragma unroll
            for (int ni = 0; ni < 2; ++ni)
                acc[mi][ni] = __builtin_amdgcn_mfma_f32_16x16x32_bf16(
                    af[mi], bf[ni], acc[mi][ni], 0, 0, 0);
        __builtin_amdgcn_s_setprio(0);
        BAR();
        scur = scur + 1 == 3 ? 0 : scur + 1;
    }

    float* Cf = (z == 0) ? Cf0 : Cf1;
    const int colg0 = bcol + wc * 32 + c0;
    const int rbase = brow + wr * 64 + (g << 2);
    const int seg   = qkv ? (bcol >> 10) : 0;
    const int Nw    = qkv ? 1024 : N;
    ushort* outb    = qkv ? (Cb + (size_t)seg * 4194304u) : Cb;
    #pragma unroll
    for (int ni = 0; ni < 2; ++ni) {
        const int colg = colg0 + ni * 16;
        const int colw = qkv ? (colg & 1023) : colg;
        const float bv = (z == 0) ? bias[colg] : 0.0f;
        #pragma unroll
        for (int mi = 0; mi < 4; ++mi) {
            #pragma unroll
            for (int j = 0; j < 4; ++j) {
                float v = acc[mi][ni][j] + bv;
                if (relu) v = fmaxf(v, 0.0f);
                const size_t off = (size_t)(rbase + mi * 16 + j) * Nw + colw;
                if (Cf) Cf[off] = v;
                if (Cb) outb[off] = f2bf(v);
            }
        }
    }
}

// ---------------- fused prep: X cast + 6 weight transposes + bias + mask --
__global__ __launch_bounds__(256)
void prep(const float* __restrict__ X, ushort* __restrict__ Xb,
          const float* __restrict__ Wq, const float* __restrict__ Wk,
          const float* __restrict__ Wv, const float* __restrict__ Wo,
          const float* __restrict__ W1, const float* __restrict__ W2,
          ushort* __restrict__ Wqkvt, ushort* __restrict__ Wot,
          ushort* __restrict__ W1t, ushort* __restrict__ W2t,
          const float* __restrict__ bq, const float* __restrict__ bk,
          const float* __restrict__ bv, float* __restrict__ biasqkv,
          const int* __restrict__ mask, int* __restrict__ mfl,
          float* __restrict__ maskout)
{
    const int b = blockIdx.x;
    const int tid = threadIdx.x;

    if (b < 4096) {                       // X fp32 -> bf16
        const int i = b * 256 + tid;
        float4 v = *reinterpret_cast<const float4*>(&X[(size_t)i * 4]);
        ushort4 o;
        o.x = f2bf(v.x); o.y = f2bf(v.y); o.z = f2bf(v.z); o.w = f2bf(v.w);
        *reinterpret_cast<ushort4*>(&Xb[(size_t)i * 4]) = o;
        return;
    }
    int r = b - 4096;
    const float* W = nullptr; ushort* D = nullptr;
    int K = H, N = H; float sc = 1.0f; int blin = 0;
    if (r < 4096) {
        const int which = r >> 10;
        blin = r & 1023;
        switch (which) {
            case 0: W = Wq; D = Wqkvt;               sc = 0.03125f; break;
            case 1: W = Wk; D = Wqkvt + 1024 * 1024; sc = 0.03125f; break;
            case 2: W = Wv; D = Wqkvt + 2048 * 1024; sc = 1.0f;     break;
            default: W = Wo; D = Wot;                sc = 1.0f;     break;
        }
    } else if (r < 4096 + 2048) {
        W = W1; D = W1t; K = H; N = FFN_DIM; blin = r - 4096;
    } else if (r < 4096 + 4096) {
        W = W2; D = W2t; K = FFN_DIM; N = H; blin = r - 4096 - 2048;
    }
    if (W) {
        __shared__ float t[32][33];
        const int nbx = N >> 5;
        const int bx = blin % nbx, by = blin / nbx;
        const int n0 = bx * 32, k0 = by * 32;
        const int tx = tid & 31, ty = tid >> 5;
        #pragma unroll
        for (int rr = 0; rr < 4; ++rr)
            t[ty + rr * 8][tx] = W[(size_t)(k0 + ty + rr * 8) * N + n0 + tx];
        __syncthreads();
        #pragma unroll
        for (int rr = 0; rr < 4; ++rr)
            D[(size_t)(n0 + ty + rr * 8) * K + k0 + tx] =
                f2bf(t[tx][ty + rr * 8] * sc);
        return;
    }
    r -= 8192;
    if (r < 12) {
        const int i = r * 256 + tid;
        if (i < 3072) {
            float v;
            if (i < 1024) v = bq[i] * 0.03125f;
            else if (i < 2048) v = bk[i - 1024] * 0.03125f;
            else v = bv[i - 2048];
            biasqkv[i] = v;
        }
        return;
    }
    if (r == 12) {
        if (tid < NB * 16) {
            const int n = tid >> 4, tile = tid & 15;
            int any = 0;
            for (int j = 0; j < 64; ++j)
                any |= (mask[n * LL + tile * 64 + j] == 0);
            mfl[tid] = any;
        }
        return;
    }
    {
        const int i = (r - 13) * 256 + tid;
        if (i < NB * LL) maskout[i] = (float)mask[i];
    }
}

// ---------------- per-head V transpose: [1024 j][64 d] -> [64 d][1024 j] --
__global__ __launch_bounds__(256)
void transpose_v(const ushort* __restrict__ V, ushort* __restrict__ Vt)
{
    const int nh = blockIdx.y, jt = blockIdx.x;
    const size_t base = (size_t)nh << 16;
    __shared__ ushort t[64][68];
    const int tid = threadIdx.x;
    #pragma unroll
    for (int pass = 0; pass < 4; ++pass) {
        const int j = pass * 16 + (tid >> 4);
        const int d0 = (tid & 15) * 4;
        ushort4 v = *(const ushort4*)&V[base + (size_t)(jt * 64 + j) * 64 + d0];
        t[d0 + 0][j] = v.x; t[d0 + 1][j] = v.y;
        t[d0 + 2][j] = v.z; t[d0 + 3][j] = v.w;
    }
    __syncthreads();
    #pragma unroll
    for (int pass = 0; pass < 4; ++pass) {
        const int d = pass * 16 + (tid >> 4);
        const int j0 = (tid & 15) * 4;
        ushort4 o;
        o.x = t[d][j0 + 0]; o.y = t[d][j0 + 1];
        o.z = t[d][j0 + 2]; o.w = t[d][j0 + 3];
        *(ushort4*)&Vt[base + (size_t)d * 1024 + jt * 64 + j0] = o;
    }
}

// ------------- MFMA flash attention: swapped QK^T, packed P, staged ------
// 8 waves / 128 q-rows per block: K/V staging shared by 2x the q-rows.
// Per-wave math identical to the proven round-7 structure. Do NOT replace
// LDS staging with direct global fragment reads (round-9: 45->123 us).
__global__ __launch_bounds__(512)
void attn_mfma(const ushort* __restrict__ Q, const ushort* __restrict__ K,
               const ushort* __restrict__ Vt, const int* __restrict__ mask,
               const int* __restrict__ mflags, ushort* __restrict__ ctx)
{
    const int nh = blockIdx.y;
    const int n  = nh >> 4;
    const int qb = blockIdx.x;               // 128 q-rows per block
    const size_t hb = (size_t)nh << 16;
    const ushort* Qh = Q + hb;
    const ushort* Kh = K + hb;
    const ushort* Vh = Vt + hb;
    ushort* Ch = ctx + hb;

    __shared__ ushort Ks[2][64 * 64];        // 16 KB
    __shared__ ushort Vs[2][64 * 64];        // 16 KB
    __shared__ ushort Ps[8][16 * 64];        // 16 KB

    const int tid = threadIdx.x;             // 0..511, 8 waves
    const int l = tid & 63, w = tid >> 6;
    const int g = l >> 4, c0 = l & 15;
    const int fsw = (c0 & 7) << 1;

    unsigned fbits = 0;
    #pragma unroll
    for (int tt = 0; tt < 16; ++tt)
        fbits |= (unsigned)(mflags[n * 16 + tt] != 0) << tt;

    const ushort* qrow = Qh + (size_t)(qb * 128 + w * 16 + c0) * 64;
    const bf16x8 qf0 = *(const bf16x8*)(qrow + g * 8);
    const bf16x8 qf1 = *(const bf16x8*)(qrow + 32 + g * 8);

    f32x4 Oacc[4];
    #pragma unroll
    for (int nd = 0; nd < 4; ++nd) Oacc[nd] = (f32x4)0.0f;
    float lp = 0.0f;

    auto stage = [&](int buf, int t) {       // 1 K + 1 V GLL per thread
        const int r = tid >> 3, p = tid & 7; // 512 chunks each
        const int c = p ^ (r & 7);
        const ushort* gk = Kh + (size_t)(t * 64 + r) * 64 + c * 8;
        const ushort* gv = Vh + (size_t)r * 1024 + t * 64 + c * 8;
        ushort* lk = Ks[buf] + (size_t)(w * 64) * 8;
        ushort* lv = Vs[buf] + (size_t)(w * 64) * 8;
        GLL(gk, lk);
        GLL(gv, lv);
    };

    stage(0, 0);
    int cur = 0;
    for (int t = 0; t < 16; ++t) {
        if (t < 15) { stage(cur ^ 1, t + 1); WAITV2(); }
        else        { WAITV0(); }
        BAR();

        // S^T = K @ Q^T : col = q = c0; rows = keys 16nb + 4g + jr
        f32x4 s[4];
        #pragma unroll
        for (int nb = 0; nb < 4; ++nb) {
            s[nb] = (f32x4)0.0f;
            const int row = nb * 16 + c0;
            const int cc0 = g ^ (row & 7);
            const int cc1 = (4 + g) ^ (row & 7);
            bf16x8 kf0 = *(const bf16x8*)&Ks[cur][row * 64 + cc0 * 8];
            bf16x8 kf1 = *(const bf16x8*)&Ks[cur][row * 64 + cc1 * 8];
            __builtin_amdgcn_s_setprio(1);
            s[nb] = __builtin_amdgcn_mfma_f32_16x16x32_bf16(kf0, qf0, s[nb], 0, 0, 0);
            s[nb] = __builtin_amdgcn_mfma_f32_16x16x32_bf16(kf1, qf1, s[nb], 0, 0, 0);
            __builtin_amdgcn_s_setprio(0);
        }
        if (fbits >> t & 1) {             // uniform branch; rare path
            #pragma unroll
            for (int nb = 0; nb < 4; ++nb)
                #pragma unroll
                for (int jr = 0; jr < 4; ++jr) {
                    const int key = 16 * nb + 4 * g + jr;
                    if (mask[n * LL + t * 64 + key] == 0)
                        s[nb][jr] = -INFINITY;
                }
        }
        // fixed-max softmax: P = exp(s); per-lane scalar row-sum (q = c0)
        #pragma unroll
        for (int nb = 0; nb < 4; ++nb)
            #pragma unroll
            for (int jr = 0; jr < 4; ++jr) {
                const float pv = __expf(s[nb][jr]);
                s[nb][jr] = pv;
                lp += pv;
            }

        // P -> per-wave LDS (packed b64, granule-XOR swizzled)
        ushort* Pw = Ps[w];
        #pragma unroll
        for (int nb = 0; nb < 4; ++nb) {
            const int gi = (4 * nb + g) ^ fsw;
            uint2 pk;
            pk.x = pack2bf(s[nb][0], s[nb][1]);
            pk.y = pack2bf(s[nb][2], s[nb][3]);
            *(uint2*)&Pw[c0 * 64 + gi * 4] = pk;
        }
        const bf16x8 pa0 = *(const bf16x8*)&Pw[c0 * 64 + ((2 * g) ^ fsw) * 4];
        const bf16x8 pa1 = *(const bf16x8*)&Pw[c0 * 64 + ((8 + 2 * g) ^ fsw) * 4];
        // O += P @ V
        #pragma unroll
        for (int nd = 0; nd < 4; ++nd) {
            const int row = nd * 16 + c0;
            const int cc0 = g ^ (row & 7);
            const int cc1 = (4 + g) ^ (row & 7);
            bf16x8 vf0 = *(const bf16x8*)&Vs[cur][row * 64 + cc0 * 8];
            bf16x8 vf1 = *(const bf16x8*)&Vs[cur][row * 64 + cc1 * 8];
            __builtin_amdgcn_s_setprio(1);
            Oacc[nd] = __builtin_amdgcn_mfma_f32_16x16x32_bf16(pa0, vf0, Oacc[nd], 0, 0, 0);
            Oacc[nd] = __builtin_amdgcn_mfma_f32_16x16x32_bf16(pa1, vf1, Oacc[nd], 0, 0, 0);
            __builtin_amdgcn_s_setprio(0);
        }
        BAR();
        cur ^= 1;
    }

    float v = lp;
    v += __shfl_xor(v, 16, 64);
    v += __shfl_xor(v, 32, 64);
    float invq[4];
    #pragma unroll
    for (int jr = 0; jr < 4; ++jr) {
        const int src = 20 * g + jr;
        invq[jr] = 1.0f / __shfl(v, src, 64);
    }
    #pragma unroll
    for (int nd = 0; nd < 4; ++nd) {
        #pragma unroll
        for (int jr = 0; jr < 4; ++jr) {
            const int row = qb * 128 + w * 16 + 4 * g + jr;
            Ch[(size_t)row * 64 + nd * 16 + c0] = f2bf(Oacc[nd][jr] * invq[jr]);
        }
    }
}

// ---------------- LayerNorm + residual (optionally 2-input sum) ----------
__global__ __launch_bounds__(256)
void ln_residual(const float* __restrict__ X, const float* __restrict__ X2,
                 const float* __restrict__ g, const float* __restrict__ b,
                 float* __restrict__ outf, ushort* __restrict__ outb)
{
    const int row = blockIdx.x;
    const int tid = threadIdx.x;
    float4 xv = *reinterpret_cast<const float4*>(&X[(size_t)row * H + tid * 4]);
    if (X2) {
        float4 yv = *reinterpret_cast<const float4*>(&X2[(size_t)row * H + tid * 4]);
        xv.x += yv.x; xv.y += yv.y; xv.z += yv.z; xv.w += yv.w;
    }
    float s = xv.x + xv.y + xv.z + xv.w;
    __shared__ float red[8];
    const int lane = tid & 63, wave = tid >> 6;
    #pragma unroll
    for (int off = 32; off > 0; off >>= 1) s += __shfl_down(s, off);
    if (lane == 0) red[wave] = s;
    __syncthreads();
    if (tid == 0)
        red[0] = (red[0] + red[1] + red[2] + red[3]) * (1.0f / H);
    __syncthreads();
    const float mu = red[0];
    const float d0 = xv.x - mu, d1 = xv.y - mu, d2 = xv.z - mu, d3 = xv.w - mu;
    float s2 = d0 * d0 + d1 * d1 + d2 * d2 + d3 * d3;
    #pragma unroll
    for (int off = 32; off > 0; off >>= 1) s2 += __shfl_down(s2, off);
    if (lane == 0) red[4 + wave] = s2;
    __syncthreads();
    if (tid == 0) {
        const float var = (red[4] + red[5] + red[6] + red[7]) * (1.0f / H);
        red[4] = rsqrtf(var + EPS);
    }
    __syncthreads();
    const float rstd = red[4];
    float4 gv = *reinterpret_cast<const float4*>(&g[tid * 4]);
    float4 bv = *reinterpret_cast<const float4*>(&b[tid * 4]);
    float4 ov;
    ov.x = d0 * rstd * gv.x + bv.x + xv.x;
    ov.y = d1 * rstd * gv.y + bv.y + xv.y;
    ov.z = d2 * rstd * gv.z + bv.z + xv.z;
    ov.w = d3 * rstd * gv.w + bv.w + xv.w;
    if (outf)
        *reinterpret_cast<float4*>(&outf[(size_t)row * H + tid * 4]) = ov;
    if (outb) {
        ushort4 ob;
        ob.x = f2bf(ov.x); ob.y = f2bf(ov.y);
        ob.z = f2bf(ov.z); ob.w = f2bf(ov.w);
        *reinterpret_cast<ushort4*>(&outb[(size_t)row * H + tid * 4]) = ob;
    }
}

extern "C" void kernel_launch(void* const* d_in, const int* in_sizes, int n_in,
                              void* d_out, int out_size, void* d_ws, size_t ws_size,
                              hipStream_t stream)
{
    const float* X    = (const float*)d_in[0];
    const int*   mask = (const int*)d_in[1];
    const float* Wq   = (const float*)d_in[2];
    const float* bq   = (const float*)d_in[3];
    const float* Wk   = (const float*)d_in[4];
    const float* bk   = (const float*)d_in[5];
    const float* Wv   = (const float*)d_in[6];
    const float* bv   = (const float*)d_in[7];
    const float* Wo   = (const float*)d_in[8];
    const float* bo   = (const float*)d_in[9];
    const float* g1   = (const float*)d_in[10];
    const float* bln1 = (const float*)d_in[11];
    const float* W1   = (const float*)d_in[12];
    const float* b1   = (const float*)d_in[13];
    const float* W2   = (const float*)d_in[14];
    const float* b2   = (const float*)d_in[15];
    const float* g2   = (const float*)d_in[16];
    const float* bln2 = (const float*)d_in[17];

    char* wsb = (char*)d_ws;
    const size_t MB = 1u << 20;
    // Layout (lifetimes checked; round-12-proven):
    // [0,24)  : QKV bf16 segs (Q@0, K@8, V@16) -> P0 fp32 [0,16) -> Fb bf16
    // [16,24) : V seg -> ctxb (after transpose_v) -> x1b -> Q0-head
    // [24,32) : Xb -> P1 -> Q0-tail
    // [32,40) : Vtb -> Q1-head
    // [40,44) : W1t          [44,46): Wot    [46,48): biasqkv+mfl  (Q1 covers)
    // [48,52) : W2t          [52,58): Wqkvt
    ushort* Qb16  = (ushort*)(wsb);
    ushort* Vb16  = (ushort*)(wsb + 16 * MB);
    ushort* ctxb  = (ushort*)(wsb + 16 * MB);
    ushort* x1b   = (ushort*)(wsb + 16 * MB);
    ushort* Xb    = (ushort*)(wsb + 24 * MB);
    ushort* Vtb   = (ushort*)(wsb + 32 * MB);
    ushort* W1t   = (ushort*)(wsb + 40 * MB);
    ushort* Wot   = (ushort*)(wsb + 44 * MB);
    float*  biasqkv = (float*)(wsb + 46 * MB);
    int*    mfl     = (int*)(wsb + 46 * MB + 16384);
    ushort* W2t   = (ushort*)(wsb + 48 * MB);
    ushort* Wqkvt = (ushort*)(wsb + 52 * MB);
    float*  P0 = (float*)(wsb);
    float*  P1 = (float*)(wsb + 24 * MB);
    ushort* Fb = (ushort*)(wsb);
    float*  Q0 = (float*)(wsb + 16 * MB);
    float*  Q1 = (float*)(wsb + 32 * MB);

    dim3 blk(256), gblk(512);

    prep<<<dim3(4096 + 4096 + 2048 + 2048 + 12 + 1 + 16), blk, 0, stream>>>(
        X, Xb, Wq, Wk, Wv, Wo, W1, W2, Wqkvt, Wot, W1t, W2t,
        bq, bk, bv, biasqkv, mask, mfl,
        (float*)d_out + (size_t)M_ROWS * H);

    // fused QKV: N=3072, linear bf16 segments
    gemm_bf16<<<dim3(24, 32, 1), gblk, 0, stream>>>(
        Xb, Wqkvt, biasqkv, nullptr, nullptr, Qb16, M_ROWS, 3072, H, 0, 1);
    transpose_v<<<dim3(16, NB * HEADS), blk, 0, stream>>>(Vb16, Vtb);

    attn_mfma<<<dim3(8, NB * HEADS), gblk, 0, stream>>>(
        Qb16, Qb16 + 4194304u, Vtb, mask, mfl, ctxb);

    gemm_bf16<<<dim3(8, 32, 2), gblk, 0, stream>>>(
        ctxb, Wot, bo, P0, P1, nullptr, M_ROWS, H, H, 0, 0);
    ln_residual<<<dim3(M_ROWS), blk, 0, stream>>>(P0, P1, g1, bln1,
                                                  nullptr, x1b);

    gemm_bf16<<<dim3(16, 32, 1), gblk, 0, stream>>>(
        x1b, W1t, b1, nullptr, nullptr, Fb, M_ROWS, FFN_DIM, H, 1, 0);
    gemm_bf16<<<dim3(8, 32, 2), gblk, 0, stream>>>(
        Fb, W2t, b2, Q0, Q1, nullptr, M_ROWS, H, FFN_DIM, 0, 0);

    ln_residual<<<dim3(M_ROWS), blk, 0, stream>>>(Q0, Q1, g2, bln2,
                                                  (float*)d_out, nullptr);
}

// Round 14
// 177.029 us; speedup vs baseline: 1.5019x; 1.0043x over previous
//
#include <hip/hip_runtime.h>
#include <math.h>

#define H 1024
#define HEADS 16
#define DH 64
#define FFN_DIM 2048
#define EPS 1e-5f
#define NB 4
#define LL 1024
#define M_ROWS 4096

typedef __attribute__((ext_vector_type(8))) short bf16x8;
typedef __attribute__((ext_vector_type(4))) float f32x4;

__device__ __forceinline__ ushort f2bf(float x) {
    union { float f; unsigned u; } c; c.f = x;
    unsigned u = c.u;
    u += 0x7FFFu + ((u >> 16) & 1u);
    return (ushort)(u >> 16);
}

__device__ __forceinline__ unsigned pack2bf(float a, float b) {
    union { float f; unsigned u; } ca, cb; ca.f = a; cb.f = b;
    const unsigned ua = ca.u + 0x8000u;
    const unsigned ub = cb.u + 0x8000u;
    return (ua >> 16) | (ub & 0xFFFF0000u);
}

#define GLL(gp, lp)                                                         \
    __builtin_amdgcn_global_load_lds(                                       \
        (const __attribute__((address_space(1))) void*)(gp),                \
        (__attribute__((address_space(3))) void*)(lp), 16, 0, 0)

#define WAITV4() asm volatile("s_waitcnt vmcnt(4)" ::: "memory")
#define WAITV2() asm volatile("s_waitcnt vmcnt(2)" ::: "memory")
#define WAITV0() asm volatile("s_waitcnt vmcnt(0)" ::: "memory")
#define BAR() __builtin_amdgcn_s_barrier()

// bijective XCD swizzle (m204): contiguous grid chunk per XCD for L2 reuse
__device__ __forceinline__ void xcd_swizzle(int nx, int ny, int& bx, int& by)
{
    const int nwg = nx * ny;
    int bid = by * nx + bx;
    const int q = nwg >> 3, r = nwg & 7;
    const int xcd = bid & 7, i = bid >> 3;
    bid = (xcd < r) ? (xcd * (q + 1) + i)
                    : (r * (q + 1) + (xcd - r) * q + i);
    bx = bid % nx; by = bid / nx;
}

// ------------- bf16 MFMA GEMM: 8 waves, 3-slot pipeline (round-6 best) ---
// A: M x K bf16 row-major.  Bt: N x K bf16 row-major (B transposed).
// C = (A@B + bias) [+relu].  Split-K via gridDim.z (z==0 adds bias,
// fp32 partials to Cf0/Cf1).  qkv: output col c -> segment c/1024, linear
// token-major write.  NOTE: do NOT fuse the per-head V transpose here —
// the (N,L,H)->(N,16,L,64) reshape is a REINTERPRET: head = token>>6
// (token-derived).  Round-10 tried feature-derived heads -> absmax 8.5.
__global__ __launch_bounds__(512, 6)
void gemm_bf16(const ushort* __restrict__ A, const ushort* __restrict__ Bt,
               const float* __restrict__ bias, float* __restrict__ Cf0,
               float* __restrict__ Cf1, ushort* __restrict__ Cb,
               int M, int N, int K, int relu, int qkv)
{
    __shared__ ushort As[3][128 * 32];   // 3 x 8 KB
    __shared__ ushort Bs[3][128 * 32];
    const int tid = threadIdx.x;         // 0..511, 8 waves
    const int l = tid & 63, w = tid >> 6;
    const int wr = w >> 2, wc = w & 3;   // wave tile: 64 rows x 32 cols
    const int g = l >> 4, c0 = l & 15;
    int bxs = blockIdx.x, bys = blockIdx.y;
    xcd_swizzle(gridDim.x, gridDim.y, bxs, bys);
    const int brow = bys * 128, bcol = bxs * 128;
    const int z = blockIdx.z;
    const int Ksub = K / gridDim.z;
    const int NS = Ksub >> 5;

    const ushort* Abase = A + (size_t)brow * K + (size_t)z * Ksub;
    const ushort* Bbase = Bt + (size_t)bcol * K + (size_t)z * Ksub;

    f32x4 acc[4][2];
    #pragma unroll
    for (int mi = 0; mi < 4; ++mi)
        #pragma unroll
        for (int ni = 0; ni < 2; ++ni)
            acc[mi][ni] = (f32x4)0.0f;

    auto stage = [&](int buf, int k0) {  // 2 GLL per thread
        const int row = tid >> 2, cp = tid & 3;
        const int c = cp ^ ((row >> 1) & 3);
        const ushort* ga = Abase + (size_t)row * K + k0 + c * 8;
        const ushort* gb = Bbase + (size_t)row * K + k0 + c * 8;
        ushort* la = As[buf] + (size_t)w * 512;   // + lane*16B by HW
        ushort* lb = Bs[buf] + (size_t)w * 512;
        GLL(ga, la);
        GLL(gb, lb);
    };

    stage(0, 0);
    stage(1, 32);
    int scur = 0;
    for (int t = 0; t < NS; ++t) {
        int snext = scur + 2; if (snext >= 3) snext -= 3;
        if (t + 2 < NS) stage(snext, (t + 2) << 5);
        if (t < NS - 2)       WAITV4();
        else if (t == NS - 2) WAITV2();
        else                  WAITV0();
        BAR();

        bf16x8 af[4], bf[2];
        #pragma unroll
        for (int mi = 0; mi < 4; ++mi) {
            const int row = wr * 64 + mi * 16 + c0;
            const int cc = g ^ ((row >> 1) & 3);
            af[mi] = *(const bf16x8*)&As[scur][row * 32 + cc * 8];
        }
        #pragma unroll
        for (int ni = 0; ni < 2; ++ni) {
            const int row = wc * 32 + ni * 16 + c0;
            const int cc = g ^ ((row >> 1) & 3);
            bf[ni] = *(const bf16x8*)&Bs[scur][row * 32 + cc * 8];
        }
        __builtin_amdgcn_s_setprio(1);
        #pragma unroll
        for (int mi = 0; mi < 4; ++mi)
            #pragma unroll
            for (int ni = 0; ni < 2; ++ni)
                acc[mi][ni] = __builtin_amdgcn_mfma_f32_16x16x32_bf16(
                    af[mi], bf[ni], acc[mi][ni], 0, 0, 0);
        __builtin_amdgcn_s_setprio(0);
        BAR();
        scur = scur + 1 == 3 ? 0 : scur + 1;
    }

    float* Cf = (z == 0) ? Cf0 : Cf1;
    const int colg0 = bcol + wc * 32 + c0;
    const int rbase = brow + wr * 64 + (g << 2);
    const int seg   = qkv ? (bcol >> 10) : 0;
    const int Nw    = qkv ? 1024 : N;
    ushort* outb    = qkv ? (Cb + (size_t)seg * 4194304u) : Cb;
    #pragma unroll
    for (int ni = 0; ni < 2; ++ni) {
        const int colg = colg0 + ni * 16;
        const int colw = qkv ? (colg & 1023) : colg;
        const float bv = (z == 0) ? bias[colg] : 0.0f;
        #pragma unroll
        for (int mi = 0; mi < 4; ++mi) {
            #pragma unroll
            for (int j = 0; j < 4; ++j) {
                float v = acc[mi][ni][j] + bv;
                if (relu) v = fmaxf(v, 0.0f);
                const size_t off = (size_t)(rbase + mi * 16 + j) * Nw + colw;
                if (Cf) Cf[off] = v;
                if (Cb) outb[off] = f2bf(v);
            }
        }
    }
}

// ---------------- fused prep: X cast + 6 weight transposes + bias + mask --
__global__ __launch_bounds__(256)
void prep(const float* __restrict__ X, ushort* __restrict__ Xb,
          const float* __restrict__ Wq, const float* __restrict__ Wk,
          const float* __restrict__ Wv, const float* __restrict__ Wo,
          const float* __restrict__ W1, const float* __restrict__ W2,
          ushort* __restrict__ Wqkvt, ushort* __restrict__ Wot,
          ushort* __restrict__ W1t, ushort* __restrict__ W2t,
          const float* __restrict__ bq, const float* __restrict__ bk,
          const float* __restrict__ bv, float* __restrict__ biasqkv,
          const int* __restrict__ mask, int* __restrict__ mfl,
          float* __restrict__ maskout)
{
    const int b = blockIdx.x;
    const int tid = threadIdx.x;

    if (b < 4096) {                       // X fp32 -> bf16
        const int i = b * 256 + tid;
        float4 v = *reinterpret_cast<const float4*>(&X[(size_t)i * 4]);
        ushort4 o;
        o.x = f2bf(v.x); o.y = f2bf(v.y); o.z = f2bf(v.z); o.w = f2bf(v.w);
        *reinterpret_cast<ushort4*>(&Xb[(size_t)i * 4]) = o;
        return;
    }
    int r = b - 4096;
    const float* W = nullptr; ushort* D = nullptr;
    int K = H, N = H; float sc = 1.0f; int blin = 0;
    if (r < 4096) {
        const int which = r >> 10;
        blin = r & 1023;
        switch (which) {
            case 0: W = Wq; D = Wqkvt;               sc = 0.03125f; break;
            case 1: W = Wk; D = Wqkvt + 1024 * 1024; sc = 0.03125f; break;
            case 2: W = Wv; D = Wqkvt + 2048 * 1024; sc = 1.0f;     break;
            default: W = Wo; D = Wot;                sc = 1.0f;     break;
        }
    } else if (r < 4096 + 2048) {
        W = W1; D = W1t; K = H; N = FFN_DIM; blin = r - 4096;
    } else if (r < 4096 + 4096) {
        W = W2; D = W2t; K = FFN_DIM; N = H; blin = r - 4096 - 2048;
    }
    if (W) {
        __shared__ float t[32][33];
        const int nbx = N >> 5;
        const int bx = blin % nbx, by = blin / nbx;
        const int n0 = bx * 32, k0 = by * 32;
        const int tx = tid & 31, ty = tid >> 5;
        #pragma unroll
        for (int rr = 0; rr < 4; ++rr)
            t[ty + rr * 8][tx] = W[(size_t)(k0 + ty + rr * 8) * N + n0 + tx];
        __syncthreads();
        #pragma unroll
        for (int rr = 0; rr < 4; ++rr)
            D[(size_t)(n0 + ty + rr * 8) * K + k0 + tx] =
                f2bf(t[tx][ty + rr * 8] * sc);
        return;
    }
    r -= 8192;
    if (r < 12) {
        const int i = r * 256 + tid;
        if (i < 3072) {
            float v;
            if (i < 1024) v = bq[i] * 0.03125f;
            else if (i < 2048) v = bk[i - 1024] * 0.03125f;
            else v = bv[i - 2048];
            biasqkv[i] = v;
        }
        return;
    }
    if (r == 12) {
        if (tid < NB * 16) {
            const int n = tid >> 4, tile = tid & 15;
            int any = 0;
            for (int j = 0; j < 64; ++j)
                any |= (mask[n * LL + tile * 64 + j] == 0);
            mfl[tid] = any;
        }
        return;
    }
    {
        const int i = (r - 13) * 256 + tid;
        if (i < NB * LL) maskout[i] = (float)mask[i];
    }
}

// ---------------- per-head V transpose: [1024 j][64 d] -> [64 d][1024 j] --
__global__ __launch_bounds__(256)
void transpose_v(const ushort* __restrict__ V, ushort* __restrict__ Vt)
{
    const int nh = blockIdx.y, jt = blockIdx.x;
    const size_t base = (size_t)nh << 16;
    __shared__ ushort t[64][68];
    const int tid = threadIdx.x;
    #pragma unroll
    for (int pass = 0; pass < 4; ++pass) {
        const int j = pass * 16 + (tid >> 4);
        const int d0 = (tid & 15) * 4;
        ushort4 v = *(const ushort4*)&V[base + (size_t)(jt * 64 + j) * 64 + d0];
        t[d0 + 0][j] = v.x; t[d0 + 1][j] = v.y;
        t[d0 + 2][j] = v.z; t[d0 + 3][j] = v.w;
    }
    __syncthreads();
    #pragma unroll
    for (int pass = 0; pass < 4; ++pass) {
        const int d = pass * 16 + (tid >> 4);
        const int j0 = (tid & 15) * 4;
        ushort4 o;
        o.x = t[d][j0 + 0]; o.y = t[d][j0 + 1];
        o.z = t[d][j0 + 2]; o.w = t[d][j0 + 3];
        *(ushort4*)&Vt[base + (size_t)d * 1024 + jt * 64 + j0] = o;
    }
}

// ------------- MFMA flash attention: swapped QK^T, packed P, staged ------
// 8 waves / 128 q-rows per block: K/V staging shared by 2x the q-rows.
// Per-wave math identical to the proven round-7 structure. Do NOT replace
// LDS staging with direct global fragment reads (round-9: 45->123 us).
__global__ __launch_bounds__(512)
void attn_mfma(const ushort* __restrict__ Q, const ushort* __restrict__ K,
               const ushort* __restrict__ Vt, const int* __restrict__ mask,
               const int* __restrict__ mflags, ushort* __restrict__ ctx)
{
    const int nh = blockIdx.y;
    const int n  = nh >> 4;
    const int qb = blockIdx.x;               // 128 q-rows per block
    const size_t hb = (size_t)nh << 16;
    const ushort* Qh = Q + hb;
    const ushort* Kh = K + hb;
    const ushort* Vh = Vt + hb;
    ushort* Ch = ctx + hb;

    __shared__ ushort Ks[2][64 * 64];        // 16 KB
    __shared__ ushort Vs[2][64 * 64];        // 16 KB
    __shared__ ushort Ps[8][16 * 64];        // 16 KB

    const int tid = threadIdx.x;             // 0..511, 8 waves
    const int l = tid & 63, w = tid >> 6;
    const int g = l >> 4, c0 = l & 15;
    const int fsw = (c0 & 7) << 1;

    unsigned fbits = 0;
    #pragma unroll
    for (int tt = 0; tt < 16; ++tt)
        fbits |= (unsigned)(mflags[n * 16 + tt] != 0) << tt;

    const ushort* qrow = Qh + (size_t)(qb * 128 + w * 16 + c0) * 64;
    const bf16x8 qf0 = *(const bf16x8*)(qrow + g * 8);
    const bf16x8 qf1 = *(const bf16x8*)(qrow + 32 + g * 8);

    f32x4 Oacc[4];
    #pragma unroll
    for (int nd = 0; nd < 4; ++nd) Oacc[nd] = (f32x4)0.0f;
    float lp = 0.0f;

    auto stage = [&](int buf, int t) {       // 1 K + 1 V GLL per thread
        const int r = tid >> 3, p = tid & 7; // 512 chunks each
        const int c = p ^ (r & 7);
        const ushort* gk = Kh + (size_t)(t * 64 + r) * 64 + c * 8;
        const ushort* gv = Vh + (size_t)r * 1024 + t * 64 + c * 8;
        ushort* lk = Ks[buf] + (size_t)(w * 64) * 8;
        ushort* lv = Vs[buf] + (size_t)(w * 64) * 8;
        GLL(gk, lk);
        GLL(gv, lv);
    };

    stage(0, 0);
    int cur = 0;
    for (int t = 0; t < 16; ++t) {
        if (t < 15) { stage(cur ^ 1, t + 1); WAITV2(); }
        else        { WAITV0(); }
        BAR();

        // S^T = K @ Q^T : col = q = c0; rows = keys 16nb + 4g + jr
        f32x4 s[4];
        #pragma unroll
        for (int nb = 0; nb < 4; ++nb) {
            s[nb] = (f32x4)0.0f;
            const int row = nb * 16 + c0;
            const int cc0 = g ^ (row & 7);
            const int cc1 = (4 + g) ^ (row & 7);
            bf16x8 kf0 = *(const bf16x8*)&Ks[cur][row * 64 + cc0 * 8];
            bf16x8 kf1 = *(const bf16x8*)&Ks[cur][row * 64 + cc1 * 8];
            __builtin_amdgcn_s_setprio(1);
            s[nb] = __builtin_amdgcn_mfma_f32_16x16x32_bf16(kf0, qf0, s[nb], 0, 0, 0);
            s[nb] = __builtin_amdgcn_mfma_f32_16x16x32_bf16(kf1, qf1, s[nb], 0, 0, 0);
            __builtin_amdgcn_s_setprio(0);
        }
        if (fbits >> t & 1) {             // uniform branch; rare path
            #pragma unroll
            for (int nb = 0; nb < 4; ++nb)
                #pragma unroll
                for (int jr = 0; jr < 4; ++jr) {
                    const int key = 16 * nb + 4 * g + jr;
                    if (mask[n * LL + t * 64 + key] == 0)
                        s[nb][jr] = -INFINITY;
                }
        }
        // fixed-max softmax: P = exp(s); per-lane scalar row-sum (q = c0)
        #pragma unroll
        for (int nb = 0; nb < 4; ++nb)
            #pragma unroll
            for (int jr = 0; jr < 4; ++jr) {
                const float pv = __expf(s[nb][jr]);
                s[nb][jr] = pv;
                lp += pv;
            }

        // P -> per-wave LDS (packed b64, granule-XOR swizzled)
        ushort* Pw = Ps[w];
        #pragma unroll
        for (int nb = 0; nb < 4; ++nb) {
            const int gi = (4 * nb + g) ^ fsw;
            uint2 pk;
            pk.x = pack2bf(s[nb][0], s[nb][1]);
            pk.y = pack2bf(s[nb][2], s[nb][3]);
            *(uint2*)&Pw[c0 * 64 + gi * 4] = pk;
        }
        const bf16x8 pa0 = *(const bf16x8*)&Pw[c0 * 64 + ((2 * g) ^ fsw) * 4];
        const bf16x8 pa1 = *(const bf16x8*)&Pw[c0 * 64 + ((8 + 2 * g) ^ fsw) * 4];
        // O += P @ V
        #pragma unroll
        for (int nd = 0; nd < 4; ++nd) {
            const int row = nd * 16 + c0;
            const int cc0 = g ^ (row & 7);
            const int cc1 = (4 + g) ^ (row & 7);
            bf16x8 vf0 = *(const bf16x8*)&Vs[cur][row * 64 + cc0 * 8];
            bf16x8 vf1 = *(const bf16x8*)&Vs[cur][row * 64 + cc1 * 8];
            __builtin_amdgcn_s_setprio(1);
            Oacc[nd] = __builtin_amdgcn_mfma_f32_16x16x32_bf16(pa0, vf0, Oacc[nd], 0, 0, 0);
            Oacc[nd] = __builtin_amdgcn_mfma_f32_16x16x32_bf16(pa1, vf1, Oacc[nd], 0, 0, 0);
            __builtin_amdgcn_s_setprio(0);
        }
        BAR();
        cur ^= 1;
    }

    float v = lp;
    v += __shfl_xor(v, 16, 64);
    v += __shfl_xor(v, 32, 64);
    float invq[4];
    #pragma unroll
    for (int jr = 0; jr < 4; ++jr) {
        const int src = 20 * g + jr;
        invq[jr] = 1.0f / __shfl(v, src, 64);
    }
    #pragma unroll
    for (int nd = 0; nd < 4; ++nd) {
        #pragma unroll
        for (int jr = 0; jr < 4; ++jr) {
            const int row = qb * 128 + w * 16 + 4 * g + jr;
            Ch[(size_t)row * 64 + nd * 16 + c0] = f2bf(Oacc[nd][jr] * invq[jr]);
        }
    }
}

// ---------------- LayerNorm + residual (optionally 2-input sum) ----------
__global__ __launch_bounds__(256)
void ln_residual(const float* __restrict__ X, const float* __restrict__ X2,
                 const float* __restrict__ g, const float* __restrict__ b,
                 float* __restrict__ outf, ushort* __restrict__ outb)
{
    const int row = blockIdx.x;
    const int tid = threadIdx.x;
    float4 xv = *reinterpret_cast<const float4*>(&X[(size_t)row * H + tid * 4]);
    if (X2) {
        float4 yv = *reinterpret_cast<const float4*>(&X2[(size_t)row * H + tid * 4]);
        xv.x += yv.x; xv.y += yv.y; xv.z += yv.z; xv.w += yv.w;
    }
    float s = xv.x + xv.y + xv.z + xv.w;
    __shared__ float red[8];
    const int lane = tid & 63, wave = tid >> 6;
    #pragma unroll
    for (int off = 32; off > 0; off >>= 1) s += __shfl_down(s, off);
    if (lane == 0) red[wave] = s;
    __syncthreads();
    if (tid == 0)
        red[0] = (red[0] + red[1] + red[2] + red[3]) * (1.0f / H);
    __syncthreads();
    const float mu = red[0];
    const float d0 = xv.x - mu, d1 = xv.y - mu, d2 = xv.z - mu, d3 = xv.w - mu;
    float s2 = d0 * d0 + d1 * d1 + d2 * d2 + d3 * d3;
    #pragma unroll
    for (int off = 32; off > 0; off >>= 1) s2 += __shfl_down(s2, off);
    if (lane == 0) red[4 + wave] = s2;
    __syncthreads();
    if (tid == 0) {
        const float var = (red[4] + red[5] + red[6] + red[7]) * (1.0f / H);
        red[4] = rsqrtf(var + EPS);
    }
    __syncthreads();
    const float rstd = red[4];
    float4 gv = *reinterpret_cast<const float4*>(&g[tid * 4]);
    float4 bv = *reinterpret_cast<const float4*>(&b[tid * 4]);
    float4 ov;
    ov.x = d0 * rstd * gv.x + bv.x + xv.x;
    ov.y = d1 * rstd * gv.y + bv.y + xv.y;
    ov.z = d2 * rstd * gv.z + bv.z + xv.z;
    ov.w = d3 * rstd * gv.w + bv.w + xv.w;
    if (outf)
        *reinterpret_cast<float4*>(&outf[(size_t)row * H + tid * 4]) = ov;
    if (outb) {
        ushort4 ob;
        ob.x = f2bf(ov.x); ob.y = f2bf(ov.y);
        ob.z = f2bf(ov.z); ob.w = f2bf(ov.w);
        *reinterpret_cast<ushort4*>(&outb[(size_t)row * H + tid * 4]) = ob;
    }
}

extern "C" void kernel_launch(void* const* d_in, const int* in_sizes, int n_in,
                              void* d_out, int out_size, void* d_ws, size_t ws_size,
                              hipStream_t stream)
{
    const float* X    = (const float*)d_in[0];
    const int*   mask = (const int*)d_in[1];
    const float* Wq   = (const float*)d_in[2];
    const float* bq   = (const float*)d_in[3];
    const float* Wk   = (const float*)d_in[4];
    const float* bk   = (const float*)d_in[5];
    const float* Wv   = (const float*)d_in[6];
    const float* bv   = (const float*)d_in[7];
    const float* Wo   = (const float*)d_in[8];
    const float* bo   = (const float*)d_in[9];
    const float* g1   = (const float*)d_in[10];
    const float* bln1 = (const float*)d_in[11];
    const float* W1   = (const float*)d_in[12];
    const float* b1   = (const float*)d_in[13];
    const float* W2   = (const float*)d_in[14];
    const float* b2   = (const float*)d_in[15];
    const float* g2   = (const float*)d_in[16];
    const float* bln2 = (const float*)d_in[17];

    char* wsb = (char*)d_ws;
    const size_t MB = 1u << 20;
    // Layout (lifetimes checked; round-12-proven):
    // [0,24)  : QKV bf16 segs (Q@0, K@8, V@16) -> P0 fp32 [0,16) -> Fb bf16
    // [16,24) : V seg -> ctxb (after transpose_v) -> x1b -> Q0-head
    // [24,32) : Xb -> P1 -> Q0-tail
    // [32,40) : Vtb -> Q1-head
    // [40,44) : W1t          [44,46): Wot    [46,48): biasqkv+mfl  (Q1 covers)
    // [48,52) : W2t          [52,58): Wqkvt
    ushort* Qb16  = (ushort*)(wsb);
    ushort* Vb16  = (ushort*)(wsb + 16 * MB);
    ushort* ctxb  = (ushort*)(wsb + 16 * MB);
    ushort* x1b   = (ushort*)(wsb + 16 * MB);
    ushort* Xb    = (ushort*)(wsb + 24 * MB);
    ushort* Vtb   = (ushort*)(wsb + 32 * MB);
    ushort* W1t   = (ushort*)(wsb + 40 * MB);
    ushort* Wot   = (ushort*)(wsb + 44 * MB);
    float*  biasqkv = (float*)(wsb + 46 * MB);
    int*    mfl     = (int*)(wsb + 46 * MB + 16384);
    ushort* W2t   = (ushort*)(wsb + 48 * MB);
    ushort* Wqkvt = (ushort*)(wsb + 52 * MB);
    float*  P0 = (float*)(wsb);
    float*  P1 = (float*)(wsb + 24 * MB);
    ushort* Fb = (ushort*)(wsb);
    float*  Q0 = (float*)(wsb + 16 * MB);
    float*  Q1 = (float*)(wsb + 32 * MB);

    dim3 blk(256), gblk(512);

    prep<<<dim3(4096 + 4096 + 2048 + 2048 + 12 + 1 + 16), blk, 0, stream>>>(
        X, Xb, Wq, Wk, Wv, Wo, W1, W2, Wqkvt, Wot, W1t, W2t,
        bq, bk, bv, biasqkv, mask, mfl,
        (float*)d_out + (size_t)M_ROWS * H);

    // fused QKV: N=3072, linear bf16 segments
    gemm_bf16<<<dim3(24, 32, 1), gblk, 0, stream>>>(
        Xb, Wqkvt, biasqkv, nullptr, nullptr, Qb16, M_ROWS, 3072, H, 0, 1);
    transpose_v<<<dim3(16, NB * HEADS), blk, 0, stream>>>(Vb16, Vtb);

    attn_mfma<<<dim3(8, NB * HEADS), gblk, 0, stream>>>(
        Qb16, Qb16 + 4194304u, Vtb, mask, mfl, ctxb);

    gemm_bf16<<<dim3(8, 32, 2), gblk, 0, stream>>>(
        ctxb, Wot, bo, P0, P1, nullptr, M_ROWS, H, H, 0, 0);
    ln_residual<<<dim3(M_ROWS), blk, 0, stream>>>(P0, P1, g1, bln1,
                                                  nullptr, x1b);

    gemm_bf16<<<dim3(16, 32, 1), gblk, 0, stream>>>(
        x1b, W1t, b1, nullptr, nullptr, Fb, M_ROWS, FFN_DIM, H, 1, 0);
    gemm_bf16<<<dim3(8, 32, 2), gblk, 0, stream>>>(
        Fb, W2t, b2, Q0, Q1, nullptr, M_ROWS, H, FFN_DIM, 0, 0);

    ln_residual<<<dim3(M_ROWS), blk, 0, stream>>>(Q0, Q1, g2, bln2,
                                                  (float*)d_out, nullptr);
}